// Round 12
// baseline (1443.137 us; speedup 1.0000x reference)
//
#include <hip/hip_runtime.h>

#define N_NODES 50000
#define N_EDGES 800000
#define NLAYERS 4
#define NTILES (N_EDGES / 64)
#define NTILES2 (N_EDGES / 128)

#define K1PAD 224
#define TPITCH 72
#define SCHUNK 49    // 1024 * 49 = 50176 >= N_NODES

typedef short bf16x8 __attribute__((ext_vector_type(8)));
typedef float f32x4 __attribute__((ext_vector_type(4)));

__device__ __forceinline__ unsigned short f2b(float f) {
  union { float f; unsigned int u; } v; v.f = f;
  unsigned int u = v.u;
  return (unsigned short)((u + 0x7fffu + ((u >> 16) & 1u)) >> 16);
}
__device__ __forceinline__ float b2f(unsigned short s) {
  union { unsigned int u; float f; } v; v.u = ((unsigned int)s) << 16;
  return v.f;
}
__device__ __forceinline__ unsigned int pack2(float lo, float hi) {
  return (unsigned int)f2b(lo) | ((unsigned int)f2b(hi) << 16);
}
__device__ __forceinline__ float silu_f(float x) {
  return x / (1.0f + __expf(-x));
}

// ---------------- CSR build + edge sort (once; edge_index layer-invariant) ----------------
__global__ void k_hist(const int* __restrict__ eidx, int* __restrict__ cnt) {
  int e = blockIdx.x * 256 + threadIdx.x;
  if (e >= N_EDGES) return;
  atomicAdd(&cnt[eidx[e]], 1);
}
__global__ __launch_bounds__(1024) void k_scan(const int* __restrict__ cnt,
                                               int* __restrict__ rowptr,
                                               int* __restrict__ cur) {
  __shared__ int part[1024];
  const int t = threadIdx.x;
  const int base = t * SCHUNK;
  int s = 0;
  for (int i = 0; i < SCHUNK; i++) {
    int idx = base + i;
    s += (idx < N_NODES) ? cnt[idx] : 0;
  }
  part[t] = s;
  __syncthreads();
  for (int off = 1; off < 1024; off <<= 1) {
    int v = (t >= off) ? part[t - off] : 0;
    __syncthreads();
    part[t] += v;
    __syncthreads();
  }
  int run = (t == 0) ? 0 : part[t - 1];
  for (int i = 0; i < SCHUNK; i++) {
    int idx = base + i;
    if (idx < N_NODES) {
      rowptr[idx] = run;
      cur[idx] = run;
      run += cnt[idx];
    }
  }
  if (t == 1023) rowptr[N_NODES] = part[1023];
}
__global__ void k_scatter(const int* __restrict__ eidx, const float* __restrict__ emask,
                          int* __restrict__ cur, int* __restrict__ elist,
                          int* __restrict__ rs, int* __restrict__ cs,
                          float* __restrict__ msrt) {
  int e = blockIdx.x * 256 + threadIdx.x;
  if (e >= N_EDGES) return;
  int r = eidx[e], c = eidx[N_EDGES + e];
  int slot = atomicAdd(&cur[r], 1);
  elist[slot] = e;
  rs[slot] = r;
  cs[slot] = c;
  msrt[slot] = emask[e];
}

// ---------------- weight conversion ----------------
__global__ void k_convW1(const float* __restrict__ eW1, unsigned short* __restrict__ Wt1) {
  int id = blockIdx.x * 256 + threadIdx.x;
  if (id >= NLAYERS * 64 * K1PAD) return;
  int k = id % K1PAD; int rem = id / K1PAD; int o = rem % 64; int l = rem / 64;
  int src = (k < 128) ? k : (k < 192 ? k + 1 : (k == 192 ? 128 : -1));
  float v = (src >= 0) ? eW1[((size_t)l * 193 + src) * 64 + o] : 0.0f;
  Wt1[id] = f2b(v);
}
__global__ void k_convT(const float* __restrict__ W, unsigned short* __restrict__ Wt, int K) {
  int id = blockIdx.x * 256 + threadIdx.x;
  if (id >= NLAYERS * 64 * K) return;
  int k = id % K; int rem = id / K; int o = rem % 64; int l = rem / 64;
  Wt[id] = f2b(W[((size_t)l * K + k) * 64 + o]);
}
// head weights: W [64, O] -> Wt [16][64] bf16 (rows >= O zero)
__global__ void k_convHead(const float* __restrict__ W, unsigned short* __restrict__ Wt, int O) {
  int id = blockIdx.x * 256 + threadIdx.x;
  if (id >= 16 * 64) return;
  int k = id & 63, o = id >> 6;
  Wt[id] = (o < O) ? f2b(W[(size_t)k * O + o]) : (unsigned short)0;
}

// ---------------- embeddings ----------------
__global__ void k_h0(const float* __restrict__ hin, const float* __restrict__ W,
                     const float* __restrict__ b, float* __restrict__ h,
                     unsigned short* __restrict__ hbf) {
  int id = blockIdx.x * 256 + threadIdx.x;
  if (id >= N_NODES * 64) return;
  int n = id >> 6, j = id & 63;
  float s = b[j];
#pragma unroll
  for (int k = 0; k < 16; k++) s += hin[n * 16 + k] * W[k * 64 + j];
  h[id] = s;
  hbf[id] = f2b(s);
}
__global__ void k_e0(const float* __restrict__ ea, const float* __restrict__ W,
                     const float* __restrict__ b, const int* __restrict__ elist,
                     unsigned short* __restrict__ ebuf) {
  int id = blockIdx.x * 256 + threadIdx.x;
  if (id >= N_EDGES * 64) return;
  int pos = id >> 6, j = id & 63;
  int e = elist[pos];
  float s = b[j];
#pragma unroll
  for (int k = 0; k < 8; k++) s += ea[e * 8 + k] * W[k * 64 + j];
  ebuf[id] = f2b(s);
}

// ---------------- fused edge kernel (one layer) ----------------
// r6 structure (2-tile batching, barrier-free, wave-private, row-sorted edges,
// fused segmented aggregation, XCD swizzle). NO setprio (r11: -5%).
// NEW: 4x4-patch epilogues — B-fragment from weight row (li*4+ct) so each lane
// owns 4 consecutive channels -> 8 ds_write_b64 per GEMM epilogue instead of
// 32 scalar ds_write_u16. Plain pack2 (no inline asm), no launch_bounds cap —
// the two r5 confounders removed. LDS contents bitwise identical.
__global__ __launch_bounds__(256) void edge_kernel(
    const unsigned short* __restrict__ hbf, unsigned short* __restrict__ ebuf,
    const float* __restrict__ xin, float* __restrict__ xout,
    float* __restrict__ agg,
    const int* __restrict__ rs, const int* __restrict__ cs,
    const float* __restrict__ msrt,
    const unsigned short* __restrict__ Wt1,
    const unsigned short* __restrict__ Wt2,
    const unsigned short* __restrict__ Wtc,
    const float* __restrict__ eb1, const float* __restrict__ eb2,
    const float* __restrict__ cb1, const float* __restrict__ cw2) {
  __shared__ __attribute__((aligned(16))) unsigned short sT[128 * TPITCH];
  __shared__ __attribute__((aligned(16))) unsigned short sM[128 * TPITCH];
  __shared__ float sNdx[128 * 3];
  __shared__ float sMaskS[128];
  __shared__ int sRow[128];

  // bijective XCD swizzle (m204 formula; NTILES2 % 8 != 0)
  const int qq = NTILES2 >> 3, r8 = NTILES2 & 7;   // 781, 2
  const int xcd = blockIdx.x & 7, sidx = blockIdx.x >> 3;
  const int tile = (xcd < r8 ? xcd * (qq + 1) : r8 * (qq + 1) + (xcd - r8) * qq) + sidx;

  const int t = threadIdx.x;
  const int lane = t & 63, w = t >> 6;
  const int q = lane >> 4, li = lane & 15;
  const int rowA = w * 32 + li;         // LDS row / wave-local edge, tile A
  const int rowB = rowA + 16;           // tile B
  const int e0 = tile * 128 + rowA;
  const int e1 = e0 + 16;

  const int rA = rs[e0], cA = cs[e0];
  const int rB = rs[e1], cB = cs[e1];

  float radA = 0.f, radB = 0.f;
  if (q == 0) {
    {
      float dx0 = xin[rA * 3 + 0] - xin[cA * 3 + 0];
      float dx1 = xin[rA * 3 + 1] - xin[cA * 3 + 1];
      float dx2 = xin[rA * 3 + 2] - xin[cA * 3 + 2];
      radA = dx0 * dx0 + dx1 * dx1 + dx2 * dx2;
      float inv = 1.0f / (sqrtf(radA) + 1.0f);
      sRow[rowA] = rA;
      sMaskS[rowA] = msrt[e0];
      sNdx[rowA * 3 + 0] = dx0 * inv;
      sNdx[rowA * 3 + 1] = dx1 * inv;
      sNdx[rowA * 3 + 2] = dx2 * inv;
    }
    {
      float dx0 = xin[rB * 3 + 0] - xin[cB * 3 + 0];
      float dx1 = xin[rB * 3 + 1] - xin[cB * 3 + 1];
      float dx2 = xin[rB * 3 + 2] - xin[cB * 3 + 2];
      radB = dx0 * dx0 + dx1 * dx1 + dx2 * dx2;
      float inv = 1.0f / (sqrtf(radB) + 1.0f);
      sRow[rowB] = rB;
      sMaskS[rowB] = msrt[e1];
      sNdx[rowB * 3 + 0] = dx0 * inv;
      sNdx[rowB * 3 + 1] = dx1 * inv;
      sNdx[rowB * 3 + 2] = dx2 * inv;
    }
  }

  const unsigned short* hrA = hbf + (size_t)rA * 64;
  const unsigned short* hcA = hbf + (size_t)cA * 64;
  const unsigned short* epA = ebuf + (size_t)e0 * 64;
  const unsigned short* hrB = hbf + (size_t)rB * 64;
  const unsigned short* hcB = hbf + (size_t)cB * 64;
  const unsigned short* epB = ebuf + (size_t)e1 * 64;

  f32x4 accA[4], accB[4];
  const f32x4 zero4 = {0.f, 0.f, 0.f, 0.f};
#pragma unroll
  for (int ct = 0; ct < 4; ct++) { accA[ct] = zero4; accB[ct] = zero4; }

  // GEMM1: K = [h_row(64) | h_col(64) | e(64) | radial | pad]; B loaded once.
  // 4x4-patch: acc[ct] holds output channel li*4+ct.
  {
    bf16x8 afA[7], afB[7];
    afA[0] = *(const bf16x8*)(hrA + q * 8);
    afA[1] = *(const bf16x8*)(hrA + 32 + q * 8);
    afA[2] = *(const bf16x8*)(hcA + q * 8);
    afA[3] = *(const bf16x8*)(hcA + 32 + q * 8);
    afA[4] = *(const bf16x8*)(epA + q * 8);
    afA[5] = *(const bf16x8*)(epA + 32 + q * 8);
    afB[0] = *(const bf16x8*)(hrB + q * 8);
    afB[1] = *(const bf16x8*)(hrB + 32 + q * 8);
    afB[2] = *(const bf16x8*)(hcB + q * 8);
    afB[3] = *(const bf16x8*)(hcB + 32 + q * 8);
    afB[4] = *(const bf16x8*)(epB + q * 8);
    afB[5] = *(const bf16x8*)(epB + 32 + q * 8);
    bf16x8 a6A = {0, 0, 0, 0, 0, 0, 0, 0};
    bf16x8 a6B = {0, 0, 0, 0, 0, 0, 0, 0};
    if (q == 0) { a6A[0] = (short)f2b(radA); a6B[0] = (short)f2b(radB); }
    afA[6] = a6A; afB[6] = a6B;
#pragma unroll
    for (int ks = 0; ks < 7; ks++) {
      int kb = ks * 32 + q * 8;
#pragma unroll
      for (int ct = 0; ct < 4; ct++) {
        bf16x8 bfr = *(const bf16x8*)(Wt1 + (size_t)(li * 4 + ct) * K1PAD + kb);
        accA[ct] = __builtin_amdgcn_mfma_f32_16x16x32_bf16(afA[ks], bfr, accA[ct], 0, 0, 0);
        accB[ct] = __builtin_amdgcn_mfma_f32_16x16x32_bf16(afB[ks], bfr, accB[ct], 0, 0, 0);
      }
    }
  }
  {
    float4 b1 = *(const float4*)(eb1 + li * 4);
#pragma unroll
    for (int r2 = 0; r2 < 4; r2++) {
      int elA = w * 32 + q * 4 + r2;
      unsigned int a0 = pack2(silu_f(accA[0][r2] + b1.x), silu_f(accA[1][r2] + b1.y));
      unsigned int a1 = pack2(silu_f(accA[2][r2] + b1.z), silu_f(accA[3][r2] + b1.w));
      *(uint2*)(sT + elA * TPITCH + li * 4) = make_uint2(a0, a1);
      unsigned int c0 = pack2(silu_f(accB[0][r2] + b1.x), silu_f(accB[1][r2] + b1.y));
      unsigned int c1 = pack2(silu_f(accB[2][r2] + b1.z), silu_f(accB[3][r2] + b1.w));
      *(uint2*)(sT + (elA + 16) * TPITCH + li * 4) = make_uint2(c0, c1);
    }
  }
  // wave-private sT — no barrier

  // GEMM2 -> m
#pragma unroll
  for (int ct = 0; ct < 4; ct++) { accA[ct] = zero4; accB[ct] = zero4; }
#pragma unroll
  for (int ks = 0; ks < 2; ks++) {
    int kb = ks * 32 + q * 8;
    bf16x8 afA = *(const bf16x8*)(sT + rowA * TPITCH + kb);
    bf16x8 afB = *(const bf16x8*)(sT + rowB * TPITCH + kb);
#pragma unroll
    for (int ct = 0; ct < 4; ct++) {
      bf16x8 bfr = *(const bf16x8*)(Wt2 + (size_t)(li * 4 + ct) * 64 + kb);
      accA[ct] = __builtin_amdgcn_mfma_f32_16x16x32_bf16(afA, bfr, accA[ct], 0, 0, 0);
      accB[ct] = __builtin_amdgcn_mfma_f32_16x16x32_bf16(afB, bfr, accB[ct], 0, 0, 0);
    }
  }
  {
    float4 b2 = *(const float4*)(eb2 + li * 4);
#pragma unroll
    for (int r2 = 0; r2 < 4; r2++) {
      int elA = w * 32 + q * 4 + r2;
      int elB = elA + 16;
      float mkA = sMaskS[elA], mkB = sMaskS[elB];
      unsigned int a0 = pack2(silu_f(accA[0][r2] + b2.x) * mkA, silu_f(accA[1][r2] + b2.y) * mkA);
      unsigned int a1 = pack2(silu_f(accA[2][r2] + b2.z) * mkA, silu_f(accA[3][r2] + b2.w) * mkA);
      *(uint2*)(sM + elA * TPITCH + li * 4) = make_uint2(a0, a1);
      unsigned int c0 = pack2(silu_f(accB[0][r2] + b2.x) * mkB, silu_f(accB[1][r2] + b2.y) * mkB);
      unsigned int c1 = pack2(silu_f(accB[2][r2] + b2.z) * mkB, silu_f(accB[3][r2] + b2.w) * mkB);
      *(uint2*)(sM + elB * TPITCH + li * 4) = make_uint2(c0, c1);
    }
  }

  // write m back to ebuf (sorted rows, contiguous; wave-private rows)
  {
    int el2 = t >> 1, part = t & 1;
    const uint4* src = (const uint4*)(sM + el2 * TPITCH + part * 32);
    uint4* dst = (uint4*)(ebuf + (size_t)(tile * 128 + el2) * 64 + part * 32);
    dst[0] = src[0]; dst[1] = src[1]; dst[2] = src[2]; dst[3] = src[3];
  }

  // fused aggregation: wave-private segmented reduce over 32 contiguous sorted
  // edges (lane = channel); run-length merge -> few atomic flushes.
  {
    float accv = 0.f;
    int curRow = sRow[w * 32];
#pragma unroll
    for (int i = 0; i < 32; i++) {
      int rr = sRow[w * 32 + i];
      float v = b2f(sM[(w * 32 + i) * TPITCH + lane]);
      if (rr != curRow) {   // wave-uniform branch
        atomicAdd(&agg[(size_t)curRow * 64 + lane], accv);
        accv = 0.f;
        curRow = rr;
      }
      accv += v;
    }
    atomicAdd(&agg[(size_t)curRow * 64 + lane], accv);
  }

  // GEMM3: u = silu(m@cW1+cb1), p = u . cw2
#pragma unroll
  for (int ct = 0; ct < 4; ct++) { accA[ct] = zero4; accB[ct] = zero4; }
#pragma unroll
  for (int ks = 0; ks < 2; ks++) {
    int kb = ks * 32 + q * 8;
    bf16x8 afA = *(const bf16x8*)(sM + rowA * TPITCH + kb);
    bf16x8 afB = *(const bf16x8*)(sM + rowB * TPITCH + kb);
#pragma unroll
    for (int ct = 0; ct < 4; ct++) {
      bf16x8 bfr = *(const bf16x8*)(Wtc + (size_t)(li * 4 + ct) * 64 + kb);
      accA[ct] = __builtin_amdgcn_mfma_f32_16x16x32_bf16(afA, bfr, accA[ct], 0, 0, 0);
      accB[ct] = __builtin_amdgcn_mfma_f32_16x16x32_bf16(afB, bfr, accB[ct], 0, 0, 0);
    }
  }
  float pA[4] = {0.f, 0.f, 0.f, 0.f};
  float pB[4] = {0.f, 0.f, 0.f, 0.f};
  {
    float4 cb = *(const float4*)(cb1 + li * 4);
    float4 cw = *(const float4*)(cw2 + li * 4);
#pragma unroll
    for (int r2 = 0; r2 < 4; r2++) {
      pA[r2] += silu_f(accA[0][r2] + cb.x) * cw.x;
      pA[r2] += silu_f(accA[1][r2] + cb.y) * cw.y;
      pA[r2] += silu_f(accA[2][r2] + cb.z) * cw.z;
      pA[r2] += silu_f(accA[3][r2] + cb.w) * cw.w;
      pB[r2] += silu_f(accB[0][r2] + cb.x) * cw.x;
      pB[r2] += silu_f(accB[1][r2] + cb.y) * cw.y;
      pB[r2] += silu_f(accB[2][r2] + cb.z) * cw.z;
      pB[r2] += silu_f(accB[3][r2] + cb.w) * cw.w;
    }
  }
#pragma unroll
  for (int m = 1; m < 16; m <<= 1) {
#pragma unroll
    for (int r2 = 0; r2 < 4; r2++) {
      pA[r2] += __shfl_xor(pA[r2], m, 64);
      pB[r2] += __shfl_xor(pB[r2], m, 64);
    }
  }
  // xout scatter with in-lane run merging (sorted rows)
  if (li < 3) {
    {
      int el0 = w * 32 + q * 4;
      float accx = sNdx[el0 * 3 + li] * pA[0];
      int cr = sRow[el0];
#pragma unroll
      for (int r2 = 1; r2 < 4; r2++) {
        int el = el0 + r2;
        int rr = sRow[el];
        float tv = sNdx[el * 3 + li] * pA[r2];
        if (rr != cr) {
          atomicAdd(&xout[(size_t)cr * 3 + li], accx);
          accx = 0.f;
          cr = rr;
        }
        accx += tv;
      }
      atomicAdd(&xout[(size_t)cr * 3 + li], accx);
    }
    {
      int el0 = w * 32 + 16 + q * 4;
      float accx = sNdx[el0 * 3 + li] * pB[0];
      int cr = sRow[el0];
#pragma unroll
      for (int r2 = 1; r2 < 4; r2++) {
        int el = el0 + r2;
        int rr = sRow[el];
        float tv = sNdx[el * 3 + li] * pB[r2];
        if (rr != cr) {
          atomicAdd(&xout[(size_t)cr * 3 + li], accx);
          accx = 0.f;
          cr = rr;
        }
        accx += tv;
      }
      atomicAdd(&xout[(size_t)cr * 3 + li], accx);
    }
  }
}

// ---------------- node kernel (one layer) ----------------
// Pure streaming. Folds: (a) agg read-then-zero in place (replaces per-layer
// memset); (b) masked-x write to BOTH this layer's buffer and the next
// layer's out-buffer (replaces per-layer memcpy; last layer writes d_out).
__global__ __launch_bounds__(256) void node_kernel(
    float* __restrict__ h, unsigned short* __restrict__ hbf,
    float* __restrict__ agg,
    float* __restrict__ xout, float* __restrict__ xnext,
    const float* __restrict__ nmask,
    const unsigned short* __restrict__ Wtn1,
    const unsigned short* __restrict__ Wtn2,
    const float* __restrict__ nb1, const float* __restrict__ nb2) {
  __shared__ __attribute__((aligned(16))) unsigned short sT[64 * TPITCH];
  const int t = threadIdx.x;
  const int nb = blockIdx.x * 64;

  if (t < 192) {
    int n2 = nb + t / 3, c2 = t % 3;
    if (n2 < N_NODES) {
      size_t o = (size_t)n2 * 3 + c2;
      float v = xout[o] * nmask[n2];
      xout[o] = v;
      xnext[o] = v;
    }
  }

  const int lane = t & 63, w = t >> 6;
  const int q = lane >> 4, li = lane & 15;
  const int nrow = w * 16 + li;
  const int n = nb + nrow;
  const bool valid = (n < N_NODES);
  const f32x4 zero4 = {0.f, 0.f, 0.f, 0.f};
  const float4 f4z = make_float4(0.f, 0.f, 0.f, 0.f);

  f32x4 acc[4];
#pragma unroll
  for (int ct = 0; ct < 4; ct++) acc[ct] = zero4;

  // A = [h(64) | agg(64)]; h direct bf16, agg f32 -> bf16 in-register,
  // then zeroed in place (per-q-lane disjoint float4 ranges).
  {
    bf16x8 afs[4];
    const bf16x8 az = {0, 0, 0, 0, 0, 0, 0, 0};
    if (valid) {
      afs[0] = *(const bf16x8*)(hbf + (size_t)n * 64 + q * 8);
      afs[1] = *(const bf16x8*)(hbf + (size_t)n * 64 + 32 + q * 8);
      float* ap = agg + (size_t)n * 64;
      bf16x8 a2, a3;
#pragma unroll
      for (int j = 0; j < 8; j++) {
        a2[j] = (short)f2b(ap[q * 8 + j]);
        a3[j] = (short)f2b(ap[32 + q * 8 + j]);
      }
      afs[2] = a2; afs[3] = a3;
      *(float4*)(ap + q * 8) = f4z;
      *(float4*)(ap + q * 8 + 4) = f4z;
      *(float4*)(ap + 32 + q * 8) = f4z;
      *(float4*)(ap + 32 + q * 8 + 4) = f4z;
    } else {
      afs[0] = az; afs[1] = az; afs[2] = az; afs[3] = az;
    }
#pragma unroll
    for (int ks = 0; ks < 4; ks++) {
      int kb = ks * 32 + q * 8;
#pragma unroll
      for (int ct = 0; ct < 4; ct++) {
        bf16x8 bfr = *(const bf16x8*)(Wtn1 + (size_t)(ct * 16 + li) * 128 + kb);
        acc[ct] = __builtin_amdgcn_mfma_f32_16x16x32_bf16(afs[ks], bfr, acc[ct], 0, 0, 0);
      }
    }
  }
#pragma unroll
  for (int ct = 0; ct < 4; ct++) {
    float bias = nb1[ct * 16 + li];
#pragma unroll
    for (int r2 = 0; r2 < 4; r2++) {
      int nl = w * 16 + q * 4 + r2;
      sT[nl * TPITCH + ct * 16 + li] = f2b(silu_f(acc[ct][r2] + bias));
    }
  }
  // wave-private sT — no barrier

#pragma unroll
  for (int ct = 0; ct < 4; ct++) acc[ct] = zero4;
#pragma unroll
  for (int ks = 0; ks < 2; ks++) {
    int kb = ks * 32 + q * 8;
    bf16x8 af = *(const bf16x8*)(sT + nrow * TPITCH + kb);
#pragma unroll
    for (int ct = 0; ct < 4; ct++) {
      bf16x8 bfr = *(const bf16x8*)(Wtn2 + (size_t)(ct * 16 + li) * 64 + kb);
      acc[ct] = __builtin_amdgcn_mfma_f32_16x16x32_bf16(af, bfr, acc[ct], 0, 0, 0);
    }
  }
#pragma unroll
  for (int ct = 0; ct < 4; ct++) {
    float bias = nb2[ct * 16 + li];
#pragma unroll
    for (int r2 = 0; r2 < 4; r2++) {
      int node = nb + w * 16 + q * 4 + r2;
      if (node < N_NODES) {
        float nm = nmask[node];
        size_t o = (size_t)node * 64 + ct * 16 + li;
        float hv = (h[o] + acc[ct][r2] + bias) * nm;
        h[o] = hv;
        hbf[o] = f2b(hv);
      }
    }
  }
}

// ---------------- output heads (MFMA) ----------------
__global__ __launch_bounds__(256) void k_hout(const unsigned short* __restrict__ hbf,
                                              const unsigned short* __restrict__ WoT,
                                              const float* __restrict__ b,
                                              const float* __restrict__ nmask,
                                              float* __restrict__ out) {
  const int t = threadIdx.x, lane = t & 63, w = t >> 6;
  const int q = lane >> 4, li = lane & 15;
  const int nb = blockIdx.x * 64;
  const int n = nb + w * 16 + li;
  const bf16x8 az = {0, 0, 0, 0, 0, 0, 0, 0};
  bf16x8 a0 = az, a1 = az;
  if (n < N_NODES) {
    a0 = *(const bf16x8*)(hbf + (size_t)n * 64 + q * 8);
    a1 = *(const bf16x8*)(hbf + (size_t)n * 64 + 32 + q * 8);
  }
  bf16x8 b0 = *(const bf16x8*)(WoT + li * 64 + q * 8);
  bf16x8 b1 = *(const bf16x8*)(WoT + li * 64 + 32 + q * 8);
  f32x4 acc = {0.f, 0.f, 0.f, 0.f};
  acc = __builtin_amdgcn_mfma_f32_16x16x32_bf16(a0, b0, acc, 0, 0, 0);
  acc = __builtin_amdgcn_mfma_f32_16x16x32_bf16(a1, b1, acc, 0, 0, 0);
  float bias = b[li];
#pragma unroll
  for (int r2 = 0; r2 < 4; r2++) {
    int node = nb + w * 16 + q * 4 + r2;
    if (node < N_NODES) out[(size_t)node * 16 + li] = (acc[r2] + bias) * nmask[node];
  }
}
__global__ __launch_bounds__(256) void k_eout(const unsigned short* __restrict__ ebuf,
                                              const unsigned short* __restrict__ WoT,
                                              const float* __restrict__ b,
                                              const float* __restrict__ emask,
                                              const int* __restrict__ elist,
                                              float* __restrict__ out) {
  const int t = threadIdx.x, lane = t & 63, w = t >> 6;
  const int q = lane >> 4, li = lane & 15;
  const int eb0 = blockIdx.x * 64;
  const int e = eb0 + w * 16 + li;
  bf16x8 a0 = *(const bf16x8*)(ebuf + (size_t)e * 64 + q * 8);
  bf16x8 a1 = *(const bf16x8*)(ebuf + (size_t)e * 64 + 32 + q * 8);
  bf16x8 b0 = *(const bf16x8*)(WoT + li * 64 + q * 8);
  bf16x8 b1 = *(const bf16x8*)(WoT + li * 64 + 32 + q * 8);
  f32x4 acc = {0.f, 0.f, 0.f, 0.f};
  acc = __builtin_amdgcn_mfma_f32_16x16x32_bf16(a0, b0, acc, 0, 0, 0);
  acc = __builtin_amdgcn_mfma_f32_16x16x32_bf16(a1, b1, acc, 0, 0, 0);
  if (li < 8) {
    float bias = b[li];
#pragma unroll
    for (int r2 = 0; r2 < 4; r2++) {
      int ee = eb0 + w * 16 + q * 4 + r2;
      int orig = elist[ee];
      out[(size_t)orig * 8 + li] = (acc[r2] + bias) * emask[orig];
    }
  }
}

extern "C" void kernel_launch(void* const* d_in, const int* in_sizes, int n_in,
                              void* d_out, int out_size, void* d_ws, size_t ws_size,
                              hipStream_t stream) {
  (void)in_sizes; (void)n_in; (void)out_size; (void)ws_size;
  const float* in_h   = (const float*)d_in[0];
  const float* in_x   = (const float*)d_in[1];
  const float* in_ea  = (const float*)d_in[2];
  const float* nmask  = (const float*)d_in[3];
  const float* emask  = (const float*)d_in[4];
  const float* Wn_in  = (const float*)d_in[5];
  const float* bn_in  = (const float*)d_in[6];
  const float* Wn_out = (const float*)d_in[7];
  const float* bn_out = (const float*)d_in[8];
  const float* We_in  = (const float*)d_in[9];
  const float* be_in  = (const float*)d_in[10];
  const float* We_out = (const float*)d_in[11];
  const float* be_out = (const float*)d_in[12];
  const float* eW1    = (const float*)d_in[13];
  const float* eb1    = (const float*)d_in[14];
  const float* eW2    = (const float*)d_in[15];
  const float* eb2    = (const float*)d_in[16];
  const float* nW1    = (const float*)d_in[17];
  const float* nb1    = (const float*)d_in[18];
  const float* nW2    = (const float*)d_in[19];
  const float* nb2    = (const float*)d_in[20];
  const float* cW1    = (const float*)d_in[21];
  const float* cb1    = (const float*)d_in[22];
  const float* cW2    = (const float*)d_in[23];
  const int*   eidx   = (const int*)d_in[24];

  char* ws = (char*)d_ws;
  size_t off = 0;
  auto alloc = [&](size_t bytes) {
    size_t o = off; off = (off + bytes + 255) & ~(size_t)255; return (void*)(ws + o);
  };
  float* h             = (float*)alloc((size_t)N_NODES * 64 * 4);
  unsigned short* hbf  = (unsigned short*)alloc((size_t)N_NODES * 64 * 2);
  unsigned short* ebuf = (unsigned short*)alloc((size_t)N_EDGES * 64 * 2);
  float* agg           = (float*)alloc((size_t)N_NODES * 64 * 4);
  float* xb0           = (float*)alloc((size_t)N_NODES * 3 * 4);
  float* xb1           = (float*)alloc((size_t)N_NODES * 3 * 4);
  int* cnt             = (int*)alloc((size_t)N_NODES * 4);
  int* rowptr          = (int*)alloc((size_t)(N_NODES + 1) * 4);
  int* cur             = (int*)alloc((size_t)N_NODES * 4);
  int* elist           = (int*)alloc((size_t)N_EDGES * 4);
  int* rsorted         = (int*)alloc((size_t)N_EDGES * 4);
  int* csorted         = (int*)alloc((size_t)N_EDGES * 4);
  float* msorted       = (float*)alloc((size_t)N_EDGES * 4);
  unsigned short* Wt1  = (unsigned short*)alloc((size_t)NLAYERS * 64 * K1PAD * 2);
  unsigned short* Wt2  = (unsigned short*)alloc((size_t)NLAYERS * 64 * 64 * 2);
  unsigned short* Wtc  = (unsigned short*)alloc((size_t)NLAYERS * 64 * 64 * 2);
  unsigned short* Wtn1 = (unsigned short*)alloc((size_t)NLAYERS * 64 * 128 * 2);
  unsigned short* Wtn2 = (unsigned short*)alloc((size_t)NLAYERS * 64 * 64 * 2);
  unsigned short* WoN  = (unsigned short*)alloc((size_t)16 * 64 * 2);
  unsigned short* WoE  = (unsigned short*)alloc((size_t)16 * 64 * 2);

  float* out = (float*)d_out;

  // one-time CSR build + edge sort
  hipMemsetAsync(cnt, 0, (size_t)N_NODES * 4, stream);
  k_hist<<<(N_EDGES + 255) / 256, 256, 0, stream>>>(eidx, cnt);
  k_scan<<<1, 1024, 0, stream>>>(cnt, rowptr, cur);
  k_scatter<<<(N_EDGES + 255) / 256, 256, 0, stream>>>(eidx, emask, cur, elist,
                                                       rsorted, csorted, msorted);

  k_convW1<<<(NLAYERS * 64 * K1PAD + 255) / 256, 256, 0, stream>>>(eW1, Wt1);
  k_convT<<<(NLAYERS * 64 * 64 + 255) / 256, 256, 0, stream>>>(eW2, Wt2, 64);
  k_convT<<<(NLAYERS * 64 * 64 + 255) / 256, 256, 0, stream>>>(cW1, Wtc, 64);
  k_convT<<<(NLAYERS * 64 * 128 + 255) / 256, 256, 0, stream>>>(nW1, Wtn1, 128);
  k_convT<<<(NLAYERS * 64 * 64 + 255) / 256, 256, 0, stream>>>(nW2, Wtn2, 64);
  k_convHead<<<4, 256, 0, stream>>>(Wn_out, WoN, 16);
  k_convHead<<<4, 256, 0, stream>>>(We_out, WoE, 8);

  k_h0<<<(N_NODES * 64 + 255) / 256, 256, 0, stream>>>(in_h, Wn_in, bn_in, h, hbf);
  k_e0<<<(N_EDGES * 64 + 255) / 256, 256, 0, stream>>>(in_ea, We_in, be_in, elist, ebuf);
  // both x buffers start as in_x; node_kernel maintains the invariant.
  hipMemcpyAsync(xb0, in_x, (size_t)N_NODES * 3 * 4, hipMemcpyDeviceToDevice, stream);
  hipMemcpyAsync(xb1, in_x, (size_t)N_NODES * 3 * 4, hipMemcpyDeviceToDevice, stream);
  // agg zeroed once; node_kernel re-zeroes in place each layer after consuming
  hipMemsetAsync(agg, 0, (size_t)N_NODES * 64 * 4, stream);

  for (int l = 0; l < NLAYERS; l++) {
    float* xi = (l & 1) ? xb1 : xb0;
    float* xo = (l & 1) ? xb0 : xb1;
    edge_kernel<<<NTILES2, 256, 0, stream>>>(
        hbf, ebuf, xi, xo, agg, rsorted, csorted, msorted,
        Wt1 + (size_t)l * 64 * K1PAD, Wt2 + (size_t)l * 64 * 64, Wtc + (size_t)l * 64 * 64,
        eb1 + l * 64, eb2 + l * 64, cb1 + l * 64, cW2 + l * 64);
    float* xnext = (l == NLAYERS - 1) ? (out + 800000) : xi;
    node_kernel<<<(N_NODES + 63) / 64, 256, 0, stream>>>(
        h, hbf, agg, xo, xnext, nmask,
        Wtn1 + (size_t)l * 64 * 128, Wtn2 + (size_t)l * 64 * 64, nb1 + l * 64, nb2 + l * 64);
  }

  k_hout<<<(N_NODES + 63) / 64, 256, 0, stream>>>(hbf, WoN, bn_out, nmask, out);
  k_eout<<<NTILES, 256, 0, stream>>>(ebuf, WoE, be_out, emask, elist, out + 950000);
}

// Round 13
// 1219.110 us; speedup vs baseline: 1.1838x; 1.1838x over previous
//
#include <hip/hip_runtime.h>

#define N_NODES 50000
#define N_EDGES 800000
#define NLAYERS 4
#define NTILES (N_EDGES / 64)
#define NTILES2 (N_EDGES / 128)

#define K1PAD 224
#define TPITCH 72
#define SCHUNK 49    // 1024 * 49 = 50176 >= N_NODES

typedef short bf16x8 __attribute__((ext_vector_type(8)));
typedef float f32x4 __attribute__((ext_vector_type(4)));

__device__ __forceinline__ unsigned short f2b(float f) {
  union { float f; unsigned int u; } v; v.f = f;
  unsigned int u = v.u;
  return (unsigned short)((u + 0x7fffu + ((u >> 16) & 1u)) >> 16);
}
__device__ __forceinline__ float b2f(unsigned short s) {
  union { unsigned int u; float f; } v; v.u = ((unsigned int)s) << 16;
  return v.f;
}
__device__ __forceinline__ float silu_f(float x) {
  return x / (1.0f + __expf(-x));
}

// ---------------- CSR build + edge sort (once; edge_index layer-invariant) ----------------
__global__ void k_hist(const int* __restrict__ eidx, int* __restrict__ cnt) {
  int e = blockIdx.x * 256 + threadIdx.x;
  if (e >= N_EDGES) return;
  atomicAdd(&cnt[eidx[e]], 1);
}
__global__ __launch_bounds__(1024) void k_scan(const int* __restrict__ cnt,
                                               int* __restrict__ rowptr,
                                               int* __restrict__ cur) {
  __shared__ int part[1024];
  const int t = threadIdx.x;
  const int base = t * SCHUNK;
  int s = 0;
  for (int i = 0; i < SCHUNK; i++) {
    int idx = base + i;
    s += (idx < N_NODES) ? cnt[idx] : 0;
  }
  part[t] = s;
  __syncthreads();
  for (int off = 1; off < 1024; off <<= 1) {
    int v = (t >= off) ? part[t - off] : 0;
    __syncthreads();
    part[t] += v;
    __syncthreads();
  }
  int run = (t == 0) ? 0 : part[t - 1];
  for (int i = 0; i < SCHUNK; i++) {
    int idx = base + i;
    if (idx < N_NODES) {
      rowptr[idx] = run;
      cur[idx] = run;
      run += cnt[idx];
    }
  }
  if (t == 1023) rowptr[N_NODES] = part[1023];
}
__global__ void k_scatter(const int* __restrict__ eidx, const float* __restrict__ emask,
                          int* __restrict__ cur, int* __restrict__ elist,
                          int* __restrict__ rs, int* __restrict__ cs,
                          float* __restrict__ msrt) {
  int e = blockIdx.x * 256 + threadIdx.x;
  if (e >= N_EDGES) return;
  int r = eidx[e], c = eidx[N_EDGES + e];
  int slot = atomicAdd(&cur[r], 1);
  elist[slot] = e;
  rs[slot] = r;
  cs[slot] = c;
  msrt[slot] = emask[e];
}

// ---------------- weight conversion ----------------
__global__ void k_convW1(const float* __restrict__ eW1, unsigned short* __restrict__ Wt1) {
  int id = blockIdx.x * 256 + threadIdx.x;
  if (id >= NLAYERS * 64 * K1PAD) return;
  int k = id % K1PAD; int rem = id / K1PAD; int o = rem % 64; int l = rem / 64;
  int src = (k < 128) ? k : (k < 192 ? k + 1 : (k == 192 ? 128 : -1));
  float v = (src >= 0) ? eW1[((size_t)l * 193 + src) * 64 + o] : 0.0f;
  Wt1[id] = f2b(v);
}
__global__ void k_convT(const float* __restrict__ W, unsigned short* __restrict__ Wt, int K) {
  int id = blockIdx.x * 256 + threadIdx.x;
  if (id >= NLAYERS * 64 * K) return;
  int k = id % K; int rem = id / K; int o = rem % 64; int l = rem / 64;
  Wt[id] = f2b(W[((size_t)l * K + k) * 64 + o]);
}
// head weights: W [64, O] -> Wt [16][64] bf16 (rows >= O zero)
__global__ void k_convHead(const float* __restrict__ W, unsigned short* __restrict__ Wt, int O) {
  int id = blockIdx.x * 256 + threadIdx.x;
  if (id >= 16 * 64) return;
  int k = id & 63, o = id >> 6;
  Wt[id] = (o < O) ? f2b(W[(size_t)k * O + o]) : (unsigned short)0;
}
// edge-embed weight: We_in [8][64] -> WtE [64][32] bf16 (k >= 8 zero)
__global__ void k_convEin(const float* __restrict__ W, unsigned short* __restrict__ Wt) {
  int id = blockIdx.x * 256 + threadIdx.x;
  if (id >= 64 * 32) return;
  int k = id & 31, o = id >> 5;
  Wt[id] = (k < 8) ? f2b(W[(size_t)k * 64 + o]) : (unsigned short)0;
}

// ---------------- embeddings ----------------
__global__ void k_h0(const float* __restrict__ hin, const float* __restrict__ W,
                     const float* __restrict__ b, float* __restrict__ h,
                     unsigned short* __restrict__ hbf) {
  int id = blockIdx.x * 256 + threadIdx.x;
  if (id >= N_NODES * 64) return;
  int n = id >> 6, j = id & 63;
  float s = b[j];
#pragma unroll
  for (int k = 0; k < 16; k++) s += hin[n * 16 + k] * W[k * 64 + j];
  h[id] = s;
  hbf[id] = f2b(s);
}
// MFMA edge embedding: ebuf[pos] = ea[elist[pos]] @ We_in + be_in (sorted order)
__global__ __launch_bounds__(256) void k_e0(const float* __restrict__ ea,
                                            const unsigned short* __restrict__ WtE,
                                            const float* __restrict__ b,
                                            const int* __restrict__ elist,
                                            unsigned short* __restrict__ ebuf) {
  const int t = threadIdx.x, lane = t & 63, w = t >> 6;
  const int q = lane >> 4, li = lane & 15;
  const int pbase = blockIdx.x * 64 + w * 16;   // wave's first sorted position
  const bf16x8 az = {0, 0, 0, 0, 0, 0, 0, 0};
  bf16x8 af = az;
  if (q == 0) {
    int e = elist[pbase + li];
    const float* ap = ea + (size_t)e * 8;
#pragma unroll
    for (int j = 0; j < 8; j++) af[j] = (short)f2b(ap[j]);
  }
  f32x4 acc[4];
  const f32x4 zero4 = {0.f, 0.f, 0.f, 0.f};
#pragma unroll
  for (int ct = 0; ct < 4; ct++) {
    bf16x8 bfr = *(const bf16x8*)(WtE + (size_t)(ct * 16 + li) * 32 + q * 8);
    acc[ct] = __builtin_amdgcn_mfma_f32_16x16x32_bf16(af, bfr, zero4, 0, 0, 0);
  }
#pragma unroll
  for (int ct = 0; ct < 4; ct++) {
    float bias = b[ct * 16 + li];
#pragma unroll
    for (int r2 = 0; r2 < 4; r2++) {
      int pos = pbase + q * 4 + r2;
      ebuf[(size_t)pos * 64 + ct * 16 + li] = f2b(acc[ct][r2] + bias);
    }
  }
}

// ---------------- fused edge kernel (one layer) ----------------
// r10-proven body: 2-tile batching (32 edges/wave), barrier-free, wave-private,
// row-sorted edges, fused segmented aggregation, XCD swizzle.
// No setprio (r11: -5%), no 4x4-patch layout (r12: -15%).
__global__ __launch_bounds__(256) void edge_kernel(
    const unsigned short* __restrict__ hbf, unsigned short* __restrict__ ebuf,
    const float* __restrict__ xin, float* __restrict__ xout,
    float* __restrict__ agg,
    const int* __restrict__ rs, const int* __restrict__ cs,
    const float* __restrict__ msrt,
    const unsigned short* __restrict__ Wt1,
    const unsigned short* __restrict__ Wt2,
    const unsigned short* __restrict__ Wtc,
    const float* __restrict__ eb1, const float* __restrict__ eb2,
    const float* __restrict__ cb1, const float* __restrict__ cw2) {
  __shared__ __attribute__((aligned(16))) unsigned short sT[128 * TPITCH];
  __shared__ __attribute__((aligned(16))) unsigned short sM[128 * TPITCH];
  __shared__ float sNdx[128 * 3];
  __shared__ float sMaskS[128];
  __shared__ int sRow[128];

  // bijective XCD swizzle (m204 formula; NTILES2 % 8 != 0)
  const int qq = NTILES2 >> 3, r8 = NTILES2 & 7;   // 781, 2
  const int xcd = blockIdx.x & 7, sidx = blockIdx.x >> 3;
  const int tile = (xcd < r8 ? xcd * (qq + 1) : r8 * (qq + 1) + (xcd - r8) * qq) + sidx;

  const int t = threadIdx.x;
  const int lane = t & 63, w = t >> 6;
  const int q = lane >> 4, li = lane & 15;
  const int rowA = w * 32 + li;         // LDS row / wave-local edge, tile A
  const int rowB = rowA + 16;           // tile B
  const int e0 = tile * 128 + rowA;
  const int e1 = e0 + 16;

  const int rA = rs[e0], cA = cs[e0];
  const int rB = rs[e1], cB = cs[e1];

  float radA = 0.f, radB = 0.f;
  if (q == 0) {
    {
      float dx0 = xin[rA * 3 + 0] - xin[cA * 3 + 0];
      float dx1 = xin[rA * 3 + 1] - xin[cA * 3 + 1];
      float dx2 = xin[rA * 3 + 2] - xin[cA * 3 + 2];
      radA = dx0 * dx0 + dx1 * dx1 + dx2 * dx2;
      float inv = 1.0f / (sqrtf(radA) + 1.0f);
      sRow[rowA] = rA;
      sMaskS[rowA] = msrt[e0];
      sNdx[rowA * 3 + 0] = dx0 * inv;
      sNdx[rowA * 3 + 1] = dx1 * inv;
      sNdx[rowA * 3 + 2] = dx2 * inv;
    }
    {
      float dx0 = xin[rB * 3 + 0] - xin[cB * 3 + 0];
      float dx1 = xin[rB * 3 + 1] - xin[cB * 3 + 1];
      float dx2 = xin[rB * 3 + 2] - xin[cB * 3 + 2];
      radB = dx0 * dx0 + dx1 * dx1 + dx2 * dx2;
      float inv = 1.0f / (sqrtf(radB) + 1.0f);
      sRow[rowB] = rB;
      sMaskS[rowB] = msrt[e1];
      sNdx[rowB * 3 + 0] = dx0 * inv;
      sNdx[rowB * 3 + 1] = dx1 * inv;
      sNdx[rowB * 3 + 2] = dx2 * inv;
    }
  }

  const unsigned short* hrA = hbf + (size_t)rA * 64;
  const unsigned short* hcA = hbf + (size_t)cA * 64;
  const unsigned short* epA = ebuf + (size_t)e0 * 64;
  const unsigned short* hrB = hbf + (size_t)rB * 64;
  const unsigned short* hcB = hbf + (size_t)cB * 64;
  const unsigned short* epB = ebuf + (size_t)e1 * 64;

  f32x4 accA[4], accB[4];
  const f32x4 zero4 = {0.f, 0.f, 0.f, 0.f};
#pragma unroll
  for (int ct = 0; ct < 4; ct++) { accA[ct] = zero4; accB[ct] = zero4; }

  // GEMM1: K = [h_row(64) | h_col(64) | e(64) | radial | pad]; B loaded once
  {
    bf16x8 afA[7], afB[7];
    afA[0] = *(const bf16x8*)(hrA + q * 8);
    afA[1] = *(const bf16x8*)(hrA + 32 + q * 8);
    afA[2] = *(const bf16x8*)(hcA + q * 8);
    afA[3] = *(const bf16x8*)(hcA + 32 + q * 8);
    afA[4] = *(const bf16x8*)(epA + q * 8);
    afA[5] = *(const bf16x8*)(epA + 32 + q * 8);
    afB[0] = *(const bf16x8*)(hrB + q * 8);
    afB[1] = *(const bf16x8*)(hrB + 32 + q * 8);
    afB[2] = *(const bf16x8*)(hcB + q * 8);
    afB[3] = *(const bf16x8*)(hcB + 32 + q * 8);
    afB[4] = *(const bf16x8*)(epB + q * 8);
    afB[5] = *(const bf16x8*)(epB + 32 + q * 8);
    bf16x8 a6A = {0, 0, 0, 0, 0, 0, 0, 0};
    bf16x8 a6B = {0, 0, 0, 0, 0, 0, 0, 0};
    if (q == 0) { a6A[0] = (short)f2b(radA); a6B[0] = (short)f2b(radB); }
    afA[6] = a6A; afB[6] = a6B;
#pragma unroll
    for (int ks = 0; ks < 7; ks++) {
      int kb = ks * 32 + q * 8;
#pragma unroll
      for (int ct = 0; ct < 4; ct++) {
        bf16x8 bfr = *(const bf16x8*)(Wt1 + (size_t)(ct * 16 + li) * K1PAD + kb);
        accA[ct] = __builtin_amdgcn_mfma_f32_16x16x32_bf16(afA[ks], bfr, accA[ct], 0, 0, 0);
        accB[ct] = __builtin_amdgcn_mfma_f32_16x16x32_bf16(afB[ks], bfr, accB[ct], 0, 0, 0);
      }
    }
  }
#pragma unroll
  for (int ct = 0; ct < 4; ct++) {
    float bias = eb1[ct * 16 + li];
#pragma unroll
    for (int r2 = 0; r2 < 4; r2++) {
      int elA = w * 32 + q * 4 + r2;
      sT[elA * TPITCH + ct * 16 + li] = f2b(silu_f(accA[ct][r2] + bias));
      sT[(elA + 16) * TPITCH + ct * 16 + li] = f2b(silu_f(accB[ct][r2] + bias));
    }
  }
  // wave-private sT — no barrier

  // GEMM2 -> m
#pragma unroll
  for (int ct = 0; ct < 4; ct++) { accA[ct] = zero4; accB[ct] = zero4; }
#pragma unroll
  for (int ks = 0; ks < 2; ks++) {
    int kb = ks * 32 + q * 8;
    bf16x8 afA = *(const bf16x8*)(sT + rowA * TPITCH + kb);
    bf16x8 afB = *(const bf16x8*)(sT + rowB * TPITCH + kb);
#pragma unroll
    for (int ct = 0; ct < 4; ct++) {
      bf16x8 bfr = *(const bf16x8*)(Wt2 + (size_t)(ct * 16 + li) * 64 + kb);
      accA[ct] = __builtin_amdgcn_mfma_f32_16x16x32_bf16(afA, bfr, accA[ct], 0, 0, 0);
      accB[ct] = __builtin_amdgcn_mfma_f32_16x16x32_bf16(afB, bfr, accB[ct], 0, 0, 0);
    }
  }
#pragma unroll
  for (int ct = 0; ct < 4; ct++) {
    float bias = eb2[ct * 16 + li];
#pragma unroll
    for (int r2 = 0; r2 < 4; r2++) {
      int elA = w * 32 + q * 4 + r2;
      int elB = elA + 16;
      float vA = silu_f(accA[ct][r2] + bias) * sMaskS[elA];
      float vB = silu_f(accB[ct][r2] + bias) * sMaskS[elB];
      sM[elA * TPITCH + ct * 16 + li] = f2b(vA);
      sM[elB * TPITCH + ct * 16 + li] = f2b(vB);
    }
  }

  // write m back to ebuf (sorted rows, contiguous; wave-private rows)
  {
    int el2 = t >> 1, part = t & 1;
    const uint4* src = (const uint4*)(sM + el2 * TPITCH + part * 32);
    uint4* dst = (uint4*)(ebuf + (size_t)(tile * 128 + el2) * 64 + part * 32);
    dst[0] = src[0]; dst[1] = src[1]; dst[2] = src[2]; dst[3] = src[3];
  }

  // fused aggregation: wave-private segmented reduce over 32 contiguous sorted
  // edges (lane = channel); run-length merge -> few atomic flushes.
  {
    float accv = 0.f;
    int curRow = sRow[w * 32];
#pragma unroll
    for (int i = 0; i < 32; i++) {
      int rr = sRow[w * 32 + i];
      float v = b2f(sM[(w * 32 + i) * TPITCH + lane]);
      if (rr != curRow) {   // wave-uniform branch
        atomicAdd(&agg[(size_t)curRow * 64 + lane], accv);
        accv = 0.f;
        curRow = rr;
      }
      accv += v;
    }
    atomicAdd(&agg[(size_t)curRow * 64 + lane], accv);
  }

  // GEMM3: u = silu(m@cW1+cb1), p = u . cw2
#pragma unroll
  for (int ct = 0; ct < 4; ct++) { accA[ct] = zero4; accB[ct] = zero4; }
#pragma unroll
  for (int ks = 0; ks < 2; ks++) {
    int kb = ks * 32 + q * 8;
    bf16x8 afA = *(const bf16x8*)(sM + rowA * TPITCH + kb);
    bf16x8 afB = *(const bf16x8*)(sM + rowB * TPITCH + kb);
#pragma unroll
    for (int ct = 0; ct < 4; ct++) {
      bf16x8 bfr = *(const bf16x8*)(Wtc + (size_t)(ct * 16 + li) * 64 + kb);
      accA[ct] = __builtin_amdgcn_mfma_f32_16x16x32_bf16(afA, bfr, accA[ct], 0, 0, 0);
      accB[ct] = __builtin_amdgcn_mfma_f32_16x16x32_bf16(afB, bfr, accB[ct], 0, 0, 0);
    }
  }
  float pA[4] = {0.f, 0.f, 0.f, 0.f};
  float pB[4] = {0.f, 0.f, 0.f, 0.f};
#pragma unroll
  for (int ct = 0; ct < 4; ct++) {
    float bias = cb1[ct * 16 + li];
    float wv = cw2[ct * 16 + li];
#pragma unroll
    for (int r2 = 0; r2 < 4; r2++) {
      pA[r2] += silu_f(accA[ct][r2] + bias) * wv;
      pB[r2] += silu_f(accB[ct][r2] + bias) * wv;
    }
  }
#pragma unroll
  for (int m = 1; m < 16; m <<= 1) {
#pragma unroll
    for (int r2 = 0; r2 < 4; r2++) {
      pA[r2] += __shfl_xor(pA[r2], m, 64);
      pB[r2] += __shfl_xor(pB[r2], m, 64);
    }
  }
  // xout scatter with in-lane run merging (sorted rows)
  if (li < 3) {
    {
      int el0 = w * 32 + q * 4;
      float accx = sNdx[el0 * 3 + li] * pA[0];
      int cr = sRow[el0];
#pragma unroll
      for (int r2 = 1; r2 < 4; r2++) {
        int el = el0 + r2;
        int rr = sRow[el];
        float tv = sNdx[el * 3 + li] * pA[r2];
        if (rr != cr) {
          atomicAdd(&xout[(size_t)cr * 3 + li], accx);
          accx = 0.f;
          cr = rr;
        }
        accx += tv;
      }
      atomicAdd(&xout[(size_t)cr * 3 + li], accx);
    }
    {
      int el0 = w * 32 + 16 + q * 4;
      float accx = sNdx[el0 * 3 + li] * pB[0];
      int cr = sRow[el0];
#pragma unroll
      for (int r2 = 1; r2 < 4; r2++) {
        int el = el0 + r2;
        int rr = sRow[el];
        float tv = sNdx[el * 3 + li] * pB[r2];
        if (rr != cr) {
          atomicAdd(&xout[(size_t)cr * 3 + li], accx);
          accx = 0.f;
          cr = rr;
        }
        accx += tv;
      }
      atomicAdd(&xout[(size_t)cr * 3 + li], accx);
    }
  }
}

// ---------------- node kernel (one layer) ----------------
// Pure streaming. Folds: (a) agg read-then-zero in place (replaces per-layer
// memset); (b) masked-x write to BOTH this layer's buffer and the next
// layer's out-buffer (replaces per-layer memcpy; last layer writes d_out).
__global__ __launch_bounds__(256) void node_kernel(
    float* __restrict__ h, unsigned short* __restrict__ hbf,
    float* __restrict__ agg,
    float* __restrict__ xout, float* __restrict__ xnext,
    const float* __restrict__ nmask,
    const unsigned short* __restrict__ Wtn1,
    const unsigned short* __restrict__ Wtn2,
    const float* __restrict__ nb1, const float* __restrict__ nb2) {
  __shared__ __attribute__((aligned(16))) unsigned short sT[64 * TPITCH];
  const int t = threadIdx.x;
  const int nb = blockIdx.x * 64;

  if (t < 192) {
    int n2 = nb + t / 3, c2 = t % 3;
    if (n2 < N_NODES) {
      size_t o = (size_t)n2 * 3 + c2;
      float v = xout[o] * nmask[n2];
      xout[o] = v;
      xnext[o] = v;
    }
  }

  const int lane = t & 63, w = t >> 6;
  const int q = lane >> 4, li = lane & 15;
  const int nrow = w * 16 + li;
  const int n = nb + nrow;
  const bool valid = (n < N_NODES);
  const f32x4 zero4 = {0.f, 0.f, 0.f, 0.f};
  const float4 f4z = make_float4(0.f, 0.f, 0.f, 0.f);

  f32x4 acc[4];
#pragma unroll
  for (int ct = 0; ct < 4; ct++) acc[ct] = zero4;

  // A = [h(64) | agg(64)]; h direct bf16, agg f32 -> bf16 in-register,
  // then zeroed in place (per-q-lane disjoint float4 ranges).
  {
    bf16x8 afs[4];
    const bf16x8 az = {0, 0, 0, 0, 0, 0, 0, 0};
    if (valid) {
      afs[0] = *(const bf16x8*)(hbf + (size_t)n * 64 + q * 8);
      afs[1] = *(const bf16x8*)(hbf + (size_t)n * 64 + 32 + q * 8);
      float* ap = agg + (size_t)n * 64;
      bf16x8 a2, a3;
#pragma unroll
      for (int j = 0; j < 8; j++) {
        a2[j] = (short)f2b(ap[q * 8 + j]);
        a3[j] = (short)f2b(ap[32 + q * 8 + j]);
      }
      afs[2] = a2; afs[3] = a3;
      *(float4*)(ap + q * 8) = f4z;
      *(float4*)(ap + q * 8 + 4) = f4z;
      *(float4*)(ap + 32 + q * 8) = f4z;
      *(float4*)(ap + 32 + q * 8 + 4) = f4z;
    } else {
      afs[0] = az; afs[1] = az; afs[2] = az; afs[3] = az;
    }
#pragma unroll
    for (int ks = 0; ks < 4; ks++) {
      int kb = ks * 32 + q * 8;
#pragma unroll
      for (int ct = 0; ct < 4; ct++) {
        bf16x8 bfr = *(const bf16x8*)(Wtn1 + (size_t)(ct * 16 + li) * 128 + kb);
        acc[ct] = __builtin_amdgcn_mfma_f32_16x16x32_bf16(afs[ks], bfr, acc[ct], 0, 0, 0);
      }
    }
  }
#pragma unroll
  for (int ct = 0; ct < 4; ct++) {
    float bias = nb1[ct * 16 + li];
#pragma unroll
    for (int r2 = 0; r2 < 4; r2++) {
      int nl = w * 16 + q * 4 + r2;
      sT[nl * TPITCH + ct * 16 + li] = f2b(silu_f(acc[ct][r2] + bias));
    }
  }
  // wave-private sT — no barrier

#pragma unroll
  for (int ct = 0; ct < 4; ct++) acc[ct] = zero4;
#pragma unroll
  for (int ks = 0; ks < 2; ks++) {
    int kb = ks * 32 + q * 8;
    bf16x8 af = *(const bf16x8*)(sT + nrow * TPITCH + kb);
#pragma unroll
    for (int ct = 0; ct < 4; ct++) {
      bf16x8 bfr = *(const bf16x8*)(Wtn2 + (size_t)(ct * 16 + li) * 64 + kb);
      acc[ct] = __builtin_amdgcn_mfma_f32_16x16x32_bf16(af, bfr, acc[ct], 0, 0, 0);
    }
  }
#pragma unroll
  for (int ct = 0; ct < 4; ct++) {
    float bias = nb2[ct * 16 + li];
#pragma unroll
    for (int r2 = 0; r2 < 4; r2++) {
      int node = nb + w * 16 + q * 4 + r2;
      if (node < N_NODES) {
        float nm = nmask[node];
        size_t o = (size_t)node * 64 + ct * 16 + li;
        float hv = (h[o] + acc[ct][r2] + bias) * nm;
        h[o] = hv;
        hbf[o] = f2b(hv);
      }
    }
  }
}

// ---------------- output heads (MFMA) ----------------
__global__ __launch_bounds__(256) void k_hout(const unsigned short* __restrict__ hbf,
                                              const unsigned short* __restrict__ WoT,
                                              const float* __restrict__ b,
                                              const float* __restrict__ nmask,
                                              float* __restrict__ out) {
  const int t = threadIdx.x, lane = t & 63, w = t >> 6;
  const int q = lane >> 4, li = lane & 15;
  const int nb = blockIdx.x * 64;
  const int n = nb + w * 16 + li;
  const bf16x8 az = {0, 0, 0, 0, 0, 0, 0, 0};
  bf16x8 a0 = az, a1 = az;
  if (n < N_NODES) {
    a0 = *(const bf16x8*)(hbf + (size_t)n * 64 + q * 8);
    a1 = *(const bf16x8*)(hbf + (size_t)n * 64 + 32 + q * 8);
  }
  bf16x8 b0 = *(const bf16x8*)(WoT + li * 64 + q * 8);
  bf16x8 b1 = *(const bf16x8*)(WoT + li * 64 + 32 + q * 8);
  f32x4 acc = {0.f, 0.f, 0.f, 0.f};
  acc = __builtin_amdgcn_mfma_f32_16x16x32_bf16(a0, b0, acc, 0, 0, 0);
  acc = __builtin_amdgcn_mfma_f32_16x16x32_bf16(a1, b1, acc, 0, 0, 0);
  float bias = b[li];
#pragma unroll
  for (int r2 = 0; r2 < 4; r2++) {
    int node = nb + w * 16 + q * 4 + r2;
    if (node < N_NODES) out[(size_t)node * 16 + li] = (acc[r2] + bias) * nmask[node];
  }
}
__global__ __launch_bounds__(256) void k_eout(const unsigned short* __restrict__ ebuf,
                                              const unsigned short* __restrict__ WoT,
                                              const float* __restrict__ b,
                                              const float* __restrict__ emask,
                                              const int* __restrict__ elist,
                                              float* __restrict__ out) {
  const int t = threadIdx.x, lane = t & 63, w = t >> 6;
  const int q = lane >> 4, li = lane & 15;
  const int eb0 = blockIdx.x * 64;
  const int e = eb0 + w * 16 + li;
  bf16x8 a0 = *(const bf16x8*)(ebuf + (size_t)e * 64 + q * 8);
  bf16x8 a1 = *(const bf16x8*)(ebuf + (size_t)e * 64 + 32 + q * 8);
  bf16x8 b0 = *(const bf16x8*)(WoT + li * 64 + q * 8);
  bf16x8 b1 = *(const bf16x8*)(WoT + li * 64 + 32 + q * 8);
  f32x4 acc = {0.f, 0.f, 0.f, 0.f};
  acc = __builtin_amdgcn_mfma_f32_16x16x32_bf16(a0, b0, acc, 0, 0, 0);
  acc = __builtin_amdgcn_mfma_f32_16x16x32_bf16(a1, b1, acc, 0, 0, 0);
  if (li < 8) {
    float bias = b[li];
#pragma unroll
    for (int r2 = 0; r2 < 4; r2++) {
      int ee = eb0 + w * 16 + q * 4 + r2;
      int orig = elist[ee];
      out[(size_t)orig * 8 + li] = (acc[r2] + bias) * emask[orig];
    }
  }
}

extern "C" void kernel_launch(void* const* d_in, const int* in_sizes, int n_in,
                              void* d_out, int out_size, void* d_ws, size_t ws_size,
                              hipStream_t stream) {
  (void)in_sizes; (void)n_in; (void)out_size; (void)ws_size;
  const float* in_h   = (const float*)d_in[0];
  const float* in_x   = (const float*)d_in[1];
  const float* in_ea  = (const float*)d_in[2];
  const float* nmask  = (const float*)d_in[3];
  const float* emask  = (const float*)d_in[4];
  const float* Wn_in  = (const float*)d_in[5];
  const float* bn_in  = (const float*)d_in[6];
  const float* Wn_out = (const float*)d_in[7];
  const float* bn_out = (const float*)d_in[8];
  const float* We_in  = (const float*)d_in[9];
  const float* be_in  = (const float*)d_in[10];
  const float* We_out = (const float*)d_in[11];
  const float* be_out = (const float*)d_in[12];
  const float* eW1    = (const float*)d_in[13];
  const float* eb1    = (const float*)d_in[14];
  const float* eW2    = (const float*)d_in[15];
  const float* eb2    = (const float*)d_in[16];
  const float* nW1    = (const float*)d_in[17];
  const float* nb1    = (const float*)d_in[18];
  const float* nW2    = (const float*)d_in[19];
  const float* nb2    = (const float*)d_in[20];
  const float* cW1    = (const float*)d_in[21];
  const float* cb1    = (const float*)d_in[22];
  const float* cW2    = (const float*)d_in[23];
  const int*   eidx   = (const int*)d_in[24];

  char* ws = (char*)d_ws;
  size_t off = 0;
  auto alloc = [&](size_t bytes) {
    size_t o = off; off = (off + bytes + 255) & ~(size_t)255; return (void*)(ws + o);
  };
  float* h             = (float*)alloc((size_t)N_NODES * 64 * 4);
  unsigned short* hbf  = (unsigned short*)alloc((size_t)N_NODES * 64 * 2);
  unsigned short* ebuf = (unsigned short*)alloc((size_t)N_EDGES * 64 * 2);
  float* agg           = (float*)alloc((size_t)N_NODES * 64 * 4);
  float* xb0           = (float*)alloc((size_t)N_NODES * 3 * 4);
  float* xb1           = (float*)alloc((size_t)N_NODES * 3 * 4);
  int* cnt             = (int*)alloc((size_t)N_NODES * 4);
  int* rowptr          = (int*)alloc((size_t)(N_NODES + 1) * 4);
  int* cur             = (int*)alloc((size_t)N_NODES * 4);
  int* elist           = (int*)alloc((size_t)N_EDGES * 4);
  int* rsorted         = (int*)alloc((size_t)N_EDGES * 4);
  int* csorted         = (int*)alloc((size_t)N_EDGES * 4);
  float* msorted       = (float*)alloc((size_t)N_EDGES * 4);
  unsigned short* Wt1  = (unsigned short*)alloc((size_t)NLAYERS * 64 * K1PAD * 2);
  unsigned short* Wt2  = (unsigned short*)alloc((size_t)NLAYERS * 64 * 64 * 2);
  unsigned short* Wtc  = (unsigned short*)alloc((size_t)NLAYERS * 64 * 64 * 2);
  unsigned short* Wtn1 = (unsigned short*)alloc((size_t)NLAYERS * 64 * 128 * 2);
  unsigned short* Wtn2 = (unsigned short*)alloc((size_t)NLAYERS * 64 * 64 * 2);
  unsigned short* WoN  = (unsigned short*)alloc((size_t)16 * 64 * 2);
  unsigned short* WoE  = (unsigned short*)alloc((size_t)16 * 64 * 2);
  unsigned short* WtE  = (unsigned short*)alloc((size_t)64 * 32 * 2);

  float* out = (float*)d_out;

  // one-time CSR build + edge sort
  hipMemsetAsync(cnt, 0, (size_t)N_NODES * 4, stream);
  k_hist<<<(N_EDGES + 255) / 256, 256, 0, stream>>>(eidx, cnt);
  k_scan<<<1, 1024, 0, stream>>>(cnt, rowptr, cur);
  k_scatter<<<(N_EDGES + 255) / 256, 256, 0, stream>>>(eidx, emask, cur, elist,
                                                       rsorted, csorted, msorted);

  k_convW1<<<(NLAYERS * 64 * K1PAD + 255) / 256, 256, 0, stream>>>(eW1, Wt1);
  k_convT<<<(NLAYERS * 64 * 64 + 255) / 256, 256, 0, stream>>>(eW2, Wt2, 64);
  k_convT<<<(NLAYERS * 64 * 64 + 255) / 256, 256, 0, stream>>>(cW1, Wtc, 64);
  k_convT<<<(NLAYERS * 64 * 128 + 255) / 256, 256, 0, stream>>>(nW1, Wtn1, 128);
  k_convT<<<(NLAYERS * 64 * 64 + 255) / 256, 256, 0, stream>>>(nW2, Wtn2, 64);
  k_convHead<<<4, 256, 0, stream>>>(Wn_out, WoN, 16);
  k_convHead<<<4, 256, 0, stream>>>(We_out, WoE, 8);
  k_convEin<<<8, 256, 0, stream>>>(We_in, WtE);

  k_h0<<<(N_NODES * 64 + 255) / 256, 256, 0, stream>>>(in_h, Wn_in, bn_in, h, hbf);
  k_e0<<<NTILES, 256, 0, stream>>>(in_ea, WtE, be_in, elist, ebuf);
  // both x buffers start as in_x; node_kernel maintains the invariant.
  hipMemcpyAsync(xb0, in_x, (size_t)N_NODES * 3 * 4, hipMemcpyDeviceToDevice, stream);
  hipMemcpyAsync(xb1, in_x, (size_t)N_NODES * 3 * 4, hipMemcpyDeviceToDevice, stream);
  // agg zeroed once; node_kernel re-zeroes in place each layer after consuming
  hipMemsetAsync(agg, 0, (size_t)N_NODES * 64 * 4, stream);

  for (int l = 0; l < NLAYERS; l++) {
    float* xi = (l & 1) ? xb1 : xb0;
    float* xo = (l & 1) ? xb0 : xb1;
    edge_kernel<<<NTILES2, 256, 0, stream>>>(
        hbf, ebuf, xi, xo, agg, rsorted, csorted, msorted,
        Wt1 + (size_t)l * 64 * K1PAD, Wt2 + (size_t)l * 64 * 64, Wtc + (size_t)l * 64 * 64,
        eb1 + l * 64, eb2 + l * 64, cb1 + l * 64, cW2 + l * 64);
    float* xnext = (l == NLAYERS - 1) ? (out + 800000) : xi;
    node_kernel<<<(N_NODES + 63) / 64, 256, 0, stream>>>(
        h, hbf, agg, xo, xnext, nmask,
        Wtn1 + (size_t)l * 64 * 128, Wtn2 + (size_t)l * 64 * 64, nb1 + l * 64, nb2 + l * 64);
  }

  k_hout<<<(N_NODES + 63) / 64, 256, 0, stream>>>(hbf, WoN, bn_out, nmask, out);
  k_eout<<<NTILES, 256, 0, stream>>>(ebuf, WoE, be_out, emask, elist, out + 950000);
}

// Round 15
// 1208.457 us; speedup vs baseline: 1.1942x; 1.0088x over previous
//
#include <hip/hip_runtime.h>

#define N_NODES 50000
#define N_EDGES 800000
#define NLAYERS 4
#define NTILES (N_EDGES / 64)
#define NTILES2 (N_EDGES / 128)

#define K1PAD 224
#define TPITCH 72
#define SCHUNK 49    // 1024 * 49 = 50176 >= N_NODES

typedef short bf16x8 __attribute__((ext_vector_type(8)));
typedef float f32x4 __attribute__((ext_vector_type(4)));

__device__ __forceinline__ unsigned short f2b(float f) {
  union { float f; unsigned int u; } v; v.f = f;
  unsigned int u = v.u;
  return (unsigned short)((u + 0x7fffu + ((u >> 16) & 1u)) >> 16);
}
__device__ __forceinline__ float b2f(unsigned short s) {
  union { unsigned int u; float f; } v; v.u = ((unsigned int)s) << 16;
  return v.f;
}
__device__ __forceinline__ float silu_f(float x) {
  return x / (1.0f + __expf(-x));
}

// ---------------- CSR build + edge sort (once; edge_index layer-invariant) ----------------
__global__ void k_hist(const int* __restrict__ eidx, int* __restrict__ cnt) {
  int e = blockIdx.x * 256 + threadIdx.x;
  if (e >= N_EDGES) return;
  atomicAdd(&cnt[eidx[e]], 1);
}
__global__ __launch_bounds__(1024) void k_scan(const int* __restrict__ cnt,
                                               int* __restrict__ rowptr,
                                               int* __restrict__ cur) {
  __shared__ int part[1024];
  const int t = threadIdx.x;
  const int base = t * SCHUNK;
  int s = 0;
  for (int i = 0; i < SCHUNK; i++) {
    int idx = base + i;
    s += (idx < N_NODES) ? cnt[idx] : 0;
  }
  part[t] = s;
  __syncthreads();
  for (int off = 1; off < 1024; off <<= 1) {
    int v = (t >= off) ? part[t - off] : 0;
    __syncthreads();
    part[t] += v;
    __syncthreads();
  }
  int run = (t == 0) ? 0 : part[t - 1];
  for (int i = 0; i < SCHUNK; i++) {
    int idx = base + i;
    if (idx < N_NODES) {
      rowptr[idx] = run;
      cur[idx] = run;
      run += cnt[idx];
    }
  }
  if (t == 1023) rowptr[N_NODES] = part[1023];
}
__global__ void k_scatter(const int* __restrict__ eidx, const float* __restrict__ emask,
                          int* __restrict__ cur, int* __restrict__ elist,
                          int* __restrict__ rs, int* __restrict__ cs,
                          float* __restrict__ msrt) {
  int e = blockIdx.x * 256 + threadIdx.x;
  if (e >= N_EDGES) return;
  int r = eidx[e], c = eidx[N_EDGES + e];
  int slot = atomicAdd(&cur[r], 1);
  elist[slot] = e;
  rs[slot] = r;
  cs[slot] = c;
  msrt[slot] = emask[e];
}

// ---------------- weight conversion ----------------
__global__ void k_convW1(const float* __restrict__ eW1, unsigned short* __restrict__ Wt1) {
  int id = blockIdx.x * 256 + threadIdx.x;
  if (id >= NLAYERS * 64 * K1PAD) return;
  int k = id % K1PAD; int rem = id / K1PAD; int o = rem % 64; int l = rem / 64;
  int src = (k < 128) ? k : (k < 192 ? k + 1 : (k == 192 ? 128 : -1));
  float v = (src >= 0) ? eW1[((size_t)l * 193 + src) * 64 + o] : 0.0f;
  Wt1[id] = f2b(v);
}
__global__ void k_convT(const float* __restrict__ W, unsigned short* __restrict__ Wt, int K) {
  int id = blockIdx.x * 256 + threadIdx.x;
  if (id >= NLAYERS * 64 * K) return;
  int k = id % K; int rem = id / K; int o = rem % 64; int l = rem / 64;
  Wt[id] = f2b(W[((size_t)l * K + k) * 64 + o]);
}
// head weights: W [64, O] -> Wt [16][64] bf16 (rows >= O zero)
__global__ void k_convHead(const float* __restrict__ W, unsigned short* __restrict__ Wt, int O) {
  int id = blockIdx.x * 256 + threadIdx.x;
  if (id >= 16 * 64) return;
  int k = id & 63, o = id >> 6;
  Wt[id] = (o < O) ? f2b(W[(size_t)k * O + o]) : (unsigned short)0;
}
// edge-embed weight: We_in [8][64] -> WtE [64][32] bf16 (k >= 8 zero)
__global__ void k_convEin(const float* __restrict__ W, unsigned short* __restrict__ Wt) {
  int id = blockIdx.x * 256 + threadIdx.x;
  if (id >= 64 * 32) return;
  int k = id & 31, o = id >> 5;
  Wt[id] = (k < 8) ? f2b(W[(size_t)k * 64 + o]) : (unsigned short)0;
}

// ---------------- embeddings ----------------
__global__ void k_h0(const float* __restrict__ hin, const float* __restrict__ W,
                     const float* __restrict__ b, float* __restrict__ h,
                     unsigned short* __restrict__ hbf) {
  int id = blockIdx.x * 256 + threadIdx.x;
  if (id >= N_NODES * 64) return;
  int n = id >> 6, j = id & 63;
  float s = b[j];
#pragma unroll
  for (int k = 0; k < 16; k++) s += hin[n * 16 + k] * W[k * 64 + j];
  h[id] = s;
  hbf[id] = f2b(s);
}
// MFMA edge embedding: ebuf[pos] = ea[elist[pos]] @ We_in + be_in (sorted order)
__global__ __launch_bounds__(256) void k_e0(const float* __restrict__ ea,
                                            const unsigned short* __restrict__ WtE,
                                            const float* __restrict__ b,
                                            const int* __restrict__ elist,
                                            unsigned short* __restrict__ ebuf) {
  const int t = threadIdx.x, lane = t & 63, w = t >> 6;
  const int q = lane >> 4, li = lane & 15;
  const int pbase = blockIdx.x * 64 + w * 16;   // wave's first sorted position
  const bf16x8 az = {0, 0, 0, 0, 0, 0, 0, 0};
  bf16x8 af = az;
  if (q == 0) {
    int e = elist[pbase + li];
    const float* ap = ea + (size_t)e * 8;
#pragma unroll
    for (int j = 0; j < 8; j++) af[j] = (short)f2b(ap[j]);
  }
  f32x4 acc[4];
  const f32x4 zero4 = {0.f, 0.f, 0.f, 0.f};
#pragma unroll
  for (int ct = 0; ct < 4; ct++) {
    bf16x8 bfr = *(const bf16x8*)(WtE + (size_t)(ct * 16 + li) * 32 + q * 8);
    acc[ct] = __builtin_amdgcn_mfma_f32_16x16x32_bf16(af, bfr, zero4, 0, 0, 0);
  }
#pragma unroll
  for (int ct = 0; ct < 4; ct++) {
    float bias = b[ct * 16 + li];
#pragma unroll
    for (int r2 = 0; r2 < 4; r2++) {
      int pos = pbase + q * 4 + r2;
      ebuf[(size_t)pos * 64 + ct * 16 + li] = f2b(acc[ct][r2] + bias);
    }
  }
}

// ---------------- fused edge kernel (one layer) ----------------
// r13-proven body (byte-identical): 2-tile batching (32 edges/wave),
// barrier-free, wave-private, row-sorted edges, LDS-loop fused aggregation,
// XCD swizzle. Numerics-preserving: r14's register-space agg changed rounding/
// summation order and broke the (thin) absmax margin — reverted.
__global__ __launch_bounds__(256) void edge_kernel(
    const unsigned short* __restrict__ hbf, unsigned short* __restrict__ ebuf,
    const float* __restrict__ xin, float* __restrict__ xout,
    float* __restrict__ agg,
    const int* __restrict__ rs, const int* __restrict__ cs,
    const float* __restrict__ msrt,
    const unsigned short* __restrict__ Wt1,
    const unsigned short* __restrict__ Wt2,
    const unsigned short* __restrict__ Wtc,
    const float* __restrict__ eb1, const float* __restrict__ eb2,
    const float* __restrict__ cb1, const float* __restrict__ cw2) {
  __shared__ __attribute__((aligned(16))) unsigned short sT[128 * TPITCH];
  __shared__ __attribute__((aligned(16))) unsigned short sM[128 * TPITCH];
  __shared__ float sNdx[128 * 3];
  __shared__ float sMaskS[128];
  __shared__ int sRow[128];

  // bijective XCD swizzle (m204 formula; NTILES2 % 8 != 0)
  const int qq = NTILES2 >> 3, r8 = NTILES2 & 7;   // 781, 2
  const int xcd = blockIdx.x & 7, sidx = blockIdx.x >> 3;
  const int tile = (xcd < r8 ? xcd * (qq + 1) : r8 * (qq + 1) + (xcd - r8) * qq) + sidx;

  const int t = threadIdx.x;
  const int lane = t & 63, w = t >> 6;
  const int q = lane >> 4, li = lane & 15;
  const int rowA = w * 32 + li;         // LDS row / wave-local edge, tile A
  const int rowB = rowA + 16;           // tile B
  const int e0 = tile * 128 + rowA;
  const int e1 = e0 + 16;

  const int rA = rs[e0], cA = cs[e0];
  const int rB = rs[e1], cB = cs[e1];

  float radA = 0.f, radB = 0.f;
  if (q == 0) {
    {
      float dx0 = xin[rA * 3 + 0] - xin[cA * 3 + 0];
      float dx1 = xin[rA * 3 + 1] - xin[cA * 3 + 1];
      float dx2 = xin[rA * 3 + 2] - xin[cA * 3 + 2];
      radA = dx0 * dx0 + dx1 * dx1 + dx2 * dx2;
      float inv = 1.0f / (sqrtf(radA) + 1.0f);
      sRow[rowA] = rA;
      sMaskS[rowA] = msrt[e0];
      sNdx[rowA * 3 + 0] = dx0 * inv;
      sNdx[rowA * 3 + 1] = dx1 * inv;
      sNdx[rowA * 3 + 2] = dx2 * inv;
    }
    {
      float dx0 = xin[rB * 3 + 0] - xin[cB * 3 + 0];
      float dx1 = xin[rB * 3 + 1] - xin[cB * 3 + 1];
      float dx2 = xin[rB * 3 + 2] - xin[cB * 3 + 2];
      radB = dx0 * dx0 + dx1 * dx1 + dx2 * dx2;
      float inv = 1.0f / (sqrtf(radB) + 1.0f);
      sRow[rowB] = rB;
      sMaskS[rowB] = msrt[e1];
      sNdx[rowB * 3 + 0] = dx0 * inv;
      sNdx[rowB * 3 + 1] = dx1 * inv;
      sNdx[rowB * 3 + 2] = dx2 * inv;
    }
  }

  const unsigned short* hrA = hbf + (size_t)rA * 64;
  const unsigned short* hcA = hbf + (size_t)cA * 64;
  const unsigned short* epA = ebuf + (size_t)e0 * 64;
  const unsigned short* hrB = hbf + (size_t)rB * 64;
  const unsigned short* hcB = hbf + (size_t)cB * 64;
  const unsigned short* epB = ebuf + (size_t)e1 * 64;

  f32x4 accA[4], accB[4];
  const f32x4 zero4 = {0.f, 0.f, 0.f, 0.f};
#pragma unroll
  for (int ct = 0; ct < 4; ct++) { accA[ct] = zero4; accB[ct] = zero4; }

  // GEMM1: K = [h_row(64) | h_col(64) | e(64) | radial | pad]; B loaded once
  {
    bf16x8 afA[7], afB[7];
    afA[0] = *(const bf16x8*)(hrA + q * 8);
    afA[1] = *(const bf16x8*)(hrA + 32 + q * 8);
    afA[2] = *(const bf16x8*)(hcA + q * 8);
    afA[3] = *(const bf16x8*)(hcA + 32 + q * 8);
    afA[4] = *(const bf16x8*)(epA + q * 8);
    afA[5] = *(const bf16x8*)(epA + 32 + q * 8);
    afB[0] = *(const bf16x8*)(hrB + q * 8);
    afB[1] = *(const bf16x8*)(hrB + 32 + q * 8);
    afB[2] = *(const bf16x8*)(hcB + q * 8);
    afB[3] = *(const bf16x8*)(hcB + 32 + q * 8);
    afB[4] = *(const bf16x8*)(epB + q * 8);
    afB[5] = *(const bf16x8*)(epB + 32 + q * 8);
    bf16x8 a6A = {0, 0, 0, 0, 0, 0, 0, 0};
    bf16x8 a6B = {0, 0, 0, 0, 0, 0, 0, 0};
    if (q == 0) { a6A[0] = (short)f2b(radA); a6B[0] = (short)f2b(radB); }
    afA[6] = a6A; afB[6] = a6B;
#pragma unroll
    for (int ks = 0; ks < 7; ks++) {
      int kb = ks * 32 + q * 8;
#pragma unroll
      for (int ct = 0; ct < 4; ct++) {
        bf16x8 bfr = *(const bf16x8*)(Wt1 + (size_t)(ct * 16 + li) * K1PAD + kb);
        accA[ct] = __builtin_amdgcn_mfma_f32_16x16x32_bf16(afA[ks], bfr, accA[ct], 0, 0, 0);
        accB[ct] = __builtin_amdgcn_mfma_f32_16x16x32_bf16(afB[ks], bfr, accB[ct], 0, 0, 0);
      }
    }
  }
#pragma unroll
  for (int ct = 0; ct < 4; ct++) {
    float bias = eb1[ct * 16 + li];
#pragma unroll
    for (int r2 = 0; r2 < 4; r2++) {
      int elA = w * 32 + q * 4 + r2;
      sT[elA * TPITCH + ct * 16 + li] = f2b(silu_f(accA[ct][r2] + bias));
      sT[(elA + 16) * TPITCH + ct * 16 + li] = f2b(silu_f(accB[ct][r2] + bias));
    }
  }
  // wave-private sT — no barrier

  // GEMM2 -> m
#pragma unroll
  for (int ct = 0; ct < 4; ct++) { accA[ct] = zero4; accB[ct] = zero4; }
#pragma unroll
  for (int ks = 0; ks < 2; ks++) {
    int kb = ks * 32 + q * 8;
    bf16x8 afA = *(const bf16x8*)(sT + rowA * TPITCH + kb);
    bf16x8 afB = *(const bf16x8*)(sT + rowB * TPITCH + kb);
#pragma unroll
    for (int ct = 0; ct < 4; ct++) {
      bf16x8 bfr = *(const bf16x8*)(Wt2 + (size_t)(ct * 16 + li) * 64 + kb);
      accA[ct] = __builtin_amdgcn_mfma_f32_16x16x32_bf16(afA, bfr, accA[ct], 0, 0, 0);
      accB[ct] = __builtin_amdgcn_mfma_f32_16x16x32_bf16(afB, bfr, accB[ct], 0, 0, 0);
    }
  }
#pragma unroll
  for (int ct = 0; ct < 4; ct++) {
    float bias = eb2[ct * 16 + li];
#pragma unroll
    for (int r2 = 0; r2 < 4; r2++) {
      int elA = w * 32 + q * 4 + r2;
      int elB = elA + 16;
      float vA = silu_f(accA[ct][r2] + bias) * sMaskS[elA];
      float vB = silu_f(accB[ct][r2] + bias) * sMaskS[elB];
      sM[elA * TPITCH + ct * 16 + li] = f2b(vA);
      sM[elB * TPITCH + ct * 16 + li] = f2b(vB);
    }
  }

  // write m back to ebuf (sorted rows, contiguous; wave-private rows)
  {
    int el2 = t >> 1, part = t & 1;
    const uint4* src = (const uint4*)(sM + el2 * TPITCH + part * 32);
    uint4* dst = (uint4*)(ebuf + (size_t)(tile * 128 + el2) * 64 + part * 32);
    dst[0] = src[0]; dst[1] = src[1]; dst[2] = src[2]; dst[3] = src[3];
  }

  // fused aggregation: wave-private segmented reduce over 32 contiguous sorted
  // edges (lane = channel); run-length merge -> few atomic flushes.
  {
    float accv = 0.f;
    int curRow = sRow[w * 32];
#pragma unroll
    for (int i = 0; i < 32; i++) {
      int rr = sRow[w * 32 + i];
      float v = b2f(sM[(w * 32 + i) * TPITCH + lane]);
      if (rr != curRow) {   // wave-uniform branch
        atomicAdd(&agg[(size_t)curRow * 64 + lane], accv);
        accv = 0.f;
        curRow = rr;
      }
      accv += v;
    }
    atomicAdd(&agg[(size_t)curRow * 64 + lane], accv);
  }

  // GEMM3: u = silu(m@cW1+cb1), p = u . cw2
#pragma unroll
  for (int ct = 0; ct < 4; ct++) { accA[ct] = zero4; accB[ct] = zero4; }
#pragma unroll
  for (int ks = 0; ks < 2; ks++) {
    int kb = ks * 32 + q * 8;
    bf16x8 afA = *(const bf16x8*)(sM + rowA * TPITCH + kb);
    bf16x8 afB = *(const bf16x8*)(sM + rowB * TPITCH + kb);
#pragma unroll
    for (int ct = 0; ct < 4; ct++) {
      bf16x8 bfr = *(const bf16x8*)(Wtc + (size_t)(ct * 16 + li) * 64 + kb);
      accA[ct] = __builtin_amdgcn_mfma_f32_16x16x32_bf16(afA, bfr, accA[ct], 0, 0, 0);
      accB[ct] = __builtin_amdgcn_mfma_f32_16x16x32_bf16(afB, bfr, accB[ct], 0, 0, 0);
    }
  }
  float pA[4] = {0.f, 0.f, 0.f, 0.f};
  float pB[4] = {0.f, 0.f, 0.f, 0.f};
#pragma unroll
  for (int ct = 0; ct < 4; ct++) {
    float bias = cb1[ct * 16 + li];
    float wv = cw2[ct * 16 + li];
#pragma unroll
    for (int r2 = 0; r2 < 4; r2++) {
      pA[r2] += silu_f(accA[ct][r2] + bias) * wv;
      pB[r2] += silu_f(accB[ct][r2] + bias) * wv;
    }
  }
#pragma unroll
  for (int m = 1; m < 16; m <<= 1) {
#pragma unroll
    for (int r2 = 0; r2 < 4; r2++) {
      pA[r2] += __shfl_xor(pA[r2], m, 64);
      pB[r2] += __shfl_xor(pB[r2], m, 64);
    }
  }
  // xout scatter with in-lane run merging (sorted rows)
  if (li < 3) {
    {
      int el0 = w * 32 + q * 4;
      float accx = sNdx[el0 * 3 + li] * pA[0];
      int cr = sRow[el0];
#pragma unroll
      for (int r2 = 1; r2 < 4; r2++) {
        int el = el0 + r2;
        int rr = sRow[el];
        float tv = sNdx[el * 3 + li] * pA[r2];
        if (rr != cr) {
          atomicAdd(&xout[(size_t)cr * 3 + li], accx);
          accx = 0.f;
          cr = rr;
        }
        accx += tv;
      }
      atomicAdd(&xout[(size_t)cr * 3 + li], accx);
    }
    {
      int el0 = w * 32 + 16 + q * 4;
      float accx = sNdx[el0 * 3 + li] * pB[0];
      int cr = sRow[el0];
#pragma unroll
      for (int r2 = 1; r2 < 4; r2++) {
        int el = el0 + r2;
        int rr = sRow[el];
        float tv = sNdx[el * 3 + li] * pB[r2];
        if (rr != cr) {
          atomicAdd(&xout[(size_t)cr * 3 + li], accx);
          accx = 0.f;
          cr = rr;
        }
        accx += tv;
      }
      atomicAdd(&xout[(size_t)cr * 3 + li], accx);
    }
  }
}

// ---------------- node kernel (one layer) ----------------
// 2-tile batching: 128 nodes/block, wave owns 32 (B-fragments feed 2 MFMAs;
// numerically identical per node to the 1-tile version — verified in r9).
// Folds: agg read-then-zero in place; masked-x write to both x buffers.
__global__ __launch_bounds__(256) void node_kernel(
    float* __restrict__ h, unsigned short* __restrict__ hbf,
    float* __restrict__ agg,
    float* __restrict__ xout, float* __restrict__ xnext,
    const float* __restrict__ nmask,
    const unsigned short* __restrict__ Wtn1,
    const unsigned short* __restrict__ Wtn2,
    const float* __restrict__ nb1, const float* __restrict__ nb2) {
  __shared__ __attribute__((aligned(16))) unsigned short sT[128 * TPITCH];
  const int t = threadIdx.x;
  const int nb = blockIdx.x * 128;

  for (int i = t; i < 128 * 3; i += 256) {
    int n2 = nb + i / 3, c2 = i % 3;
    if (n2 < N_NODES) {
      size_t o = (size_t)n2 * 3 + c2;
      float v = xout[o] * nmask[n2];
      xout[o] = v;
      xnext[o] = v;
    }
  }

  const int lane = t & 63, w = t >> 6;
  const int q = lane >> 4, li = lane & 15;
  const f32x4 zero4 = {0.f, 0.f, 0.f, 0.f};
  const float4 f4z = make_float4(0.f, 0.f, 0.f, 0.f);

  f32x4 acc[2][4];
#pragma unroll
  for (int tt = 0; tt < 2; tt++)
#pragma unroll
    for (int ct = 0; ct < 4; ct++) acc[tt][ct] = zero4;

  // A = [h(64) | agg(64)]; h direct bf16, agg f32 -> bf16 in-register,
  // then zeroed in place (per-q-lane disjoint float4 ranges).
  bf16x8 af[2][4];
  const bf16x8 az = {0, 0, 0, 0, 0, 0, 0, 0};
#pragma unroll
  for (int tt = 0; tt < 2; tt++) {
    int n = nb + w * 32 + tt * 16 + li;
    if (n < N_NODES) {
      af[tt][0] = *(const bf16x8*)(hbf + (size_t)n * 64 + q * 8);
      af[tt][1] = *(const bf16x8*)(hbf + (size_t)n * 64 + 32 + q * 8);
      float* ap = agg + (size_t)n * 64;
      bf16x8 a2, a3;
#pragma unroll
      for (int j = 0; j < 8; j++) {
        a2[j] = (short)f2b(ap[q * 8 + j]);
        a3[j] = (short)f2b(ap[32 + q * 8 + j]);
      }
      af[tt][2] = a2; af[tt][3] = a3;
      *(float4*)(ap + q * 8) = f4z;
      *(float4*)(ap + q * 8 + 4) = f4z;
      *(float4*)(ap + 32 + q * 8) = f4z;
      *(float4*)(ap + 32 + q * 8 + 4) = f4z;
    } else {
      af[tt][0] = az; af[tt][1] = az; af[tt][2] = az; af[tt][3] = az;
    }
  }
#pragma unroll
  for (int ks = 0; ks < 4; ks++) {
    int kb = ks * 32 + q * 8;
#pragma unroll
    for (int ct = 0; ct < 4; ct++) {
      bf16x8 bfr = *(const bf16x8*)(Wtn1 + (size_t)(ct * 16 + li) * 128 + kb);
#pragma unroll
      for (int tt = 0; tt < 2; tt++)
        acc[tt][ct] = __builtin_amdgcn_mfma_f32_16x16x32_bf16(af[tt][ks], bfr, acc[tt][ct], 0, 0, 0);
    }
  }
#pragma unroll
  for (int ct = 0; ct < 4; ct++) {
    float bias = nb1[ct * 16 + li];
#pragma unroll
    for (int r2 = 0; r2 < 4; r2++) {
#pragma unroll
      for (int tt = 0; tt < 2; tt++) {
        int nl = w * 32 + tt * 16 + q * 4 + r2;
        sT[nl * TPITCH + ct * 16 + li] = f2b(silu_f(acc[tt][ct][r2] + bias));
      }
    }
  }
  // wave-private sT — no barrier

#pragma unroll
  for (int tt = 0; tt < 2; tt++)
#pragma unroll
    for (int ct = 0; ct < 4; ct++) acc[tt][ct] = zero4;
#pragma unroll
  for (int ks = 0; ks < 2; ks++) {
    int kb = ks * 32 + q * 8;
    bf16x8 afr[2];
#pragma unroll
    for (int tt = 0; tt < 2; tt++)
      afr[tt] = *(const bf16x8*)(sT + (w * 32 + tt * 16 + li) * TPITCH + kb);
#pragma unroll
    for (int ct = 0; ct < 4; ct++) {
      bf16x8 bfr = *(const bf16x8*)(Wtn2 + (size_t)(ct * 16 + li) * 64 + kb);
#pragma unroll
      for (int tt = 0; tt < 2; tt++)
        acc[tt][ct] = __builtin_amdgcn_mfma_f32_16x16x32_bf16(afr[tt], bfr, acc[tt][ct], 0, 0, 0);
    }
  }
#pragma unroll
  for (int ct = 0; ct < 4; ct++) {
    float bias = nb2[ct * 16 + li];
#pragma unroll
    for (int r2 = 0; r2 < 4; r2++) {
#pragma unroll
      for (int tt = 0; tt < 2; tt++) {
        int node = nb + w * 32 + tt * 16 + q * 4 + r2;
        if (node < N_NODES) {
          float nm = nmask[node];
          size_t o = (size_t)node * 64 + ct * 16 + li;
          float hv = (h[o] + acc[tt][ct][r2] + bias) * nm;
          h[o] = hv;
          hbf[o] = f2b(hv);
        }
      }
    }
  }
}

// ---------------- output heads (MFMA) ----------------
__global__ __launch_bounds__(256) void k_hout(const unsigned short* __restrict__ hbf,
                                              const unsigned short* __restrict__ WoT,
                                              const float* __restrict__ b,
                                              const float* __restrict__ nmask,
                                              float* __restrict__ out) {
  const int t = threadIdx.x, lane = t & 63, w = t >> 6;
  const int q = lane >> 4, li = lane & 15;
  const int nb = blockIdx.x * 64;
  const int n = nb + w * 16 + li;
  const bf16x8 az = {0, 0, 0, 0, 0, 0, 0, 0};
  bf16x8 a0 = az, a1 = az;
  if (n < N_NODES) {
    a0 = *(const bf16x8*)(hbf + (size_t)n * 64 + q * 8);
    a1 = *(const bf16x8*)(hbf + (size_t)n * 64 + 32 + q * 8);
  }
  bf16x8 b0 = *(const bf16x8*)(WoT + li * 64 + q * 8);
  bf16x8 b1 = *(const bf16x8*)(WoT + li * 64 + 32 + q * 8);
  f32x4 acc = {0.f, 0.f, 0.f, 0.f};
  acc = __builtin_amdgcn_mfma_f32_16x16x32_bf16(a0, b0, acc, 0, 0, 0);
  acc = __builtin_amdgcn_mfma_f32_16x16x32_bf16(a1, b1, acc, 0, 0, 0);
  float bias = b[li];
#pragma unroll
  for (int r2 = 0; r2 < 4; r2++) {
    int node = nb + w * 16 + q * 4 + r2;
    if (node < N_NODES) out[(size_t)node * 16 + li] = (acc[r2] + bias) * nmask[node];
  }
}
__global__ __launch_bounds__(256) void k_eout(const unsigned short* __restrict__ ebuf,
                                              const unsigned short* __restrict__ WoT,
                                              const float* __restrict__ b,
                                              const float* __restrict__ emask,
                                              const int* __restrict__ elist,
                                              float* __restrict__ out) {
  const int t = threadIdx.x, lane = t & 63, w = t >> 6;
  const int q = lane >> 4, li = lane & 15;
  const int eb0 = blockIdx.x * 64;
  const int e = eb0 + w * 16 + li;
  bf16x8 a0 = *(const bf16x8*)(ebuf + (size_t)e * 64 + q * 8);
  bf16x8 a1 = *(const bf16x8*)(ebuf + (size_t)e * 64 + 32 + q * 8);
  bf16x8 b0 = *(const bf16x8*)(WoT + li * 64 + q * 8);
  bf16x8 b1 = *(const bf16x8*)(WoT + li * 64 + 32 + q * 8);
  f32x4 acc = {0.f, 0.f, 0.f, 0.f};
  acc = __builtin_amdgcn_mfma_f32_16x16x32_bf16(a0, b0, acc, 0, 0, 0);
  acc = __builtin_amdgcn_mfma_f32_16x16x32_bf16(a1, b1, acc, 0, 0, 0);
  if (li < 8) {
    float bias = b[li];
#pragma unroll
    for (int r2 = 0; r2 < 4; r2++) {
      int ee = eb0 + w * 16 + q * 4 + r2;
      int orig = elist[ee];
      out[(size_t)orig * 8 + li] = (acc[r2] + bias) * emask[orig];
    }
  }
}

extern "C" void kernel_launch(void* const* d_in, const int* in_sizes, int n_in,
                              void* d_out, int out_size, void* d_ws, size_t ws_size,
                              hipStream_t stream) {
  (void)in_sizes; (void)n_in; (void)out_size; (void)ws_size;
  const float* in_h   = (const float*)d_in[0];
  const float* in_x   = (const float*)d_in[1];
  const float* in_ea  = (const float*)d_in[2];
  const float* nmask  = (const float*)d_in[3];
  const float* emask  = (const float*)d_in[4];
  const float* Wn_in  = (const float*)d_in[5];
  const float* bn_in  = (const float*)d_in[6];
  const float* Wn_out = (const float*)d_in[7];
  const float* bn_out = (const float*)d_in[8];
  const float* We_in  = (const float*)d_in[9];
  const float* be_in  = (const float*)d_in[10];
  const float* We_out = (const float*)d_in[11];
  const float* be_out = (const float*)d_in[12];
  const float* eW1    = (const float*)d_in[13];
  const float* eb1    = (const float*)d_in[14];
  const float* eW2    = (const float*)d_in[15];
  const float* eb2    = (const float*)d_in[16];
  const float* nW1    = (const float*)d_in[17];
  const float* nb1    = (const float*)d_in[18];
  const float* nW2    = (const float*)d_in[19];
  const float* nb2    = (const float*)d_in[20];
  const float* cW1    = (const float*)d_in[21];
  const float* cb1    = (const float*)d_in[22];
  const float* cW2    = (const float*)d_in[23];
  const int*   eidx   = (const int*)d_in[24];

  char* ws = (char*)d_ws;
  size_t off = 0;
  auto alloc = [&](size_t bytes) {
    size_t o = off; off = (off + bytes + 255) & ~(size_t)255; return (void*)(ws + o);
  };
  float* h             = (float*)alloc((size_t)N_NODES * 64 * 4);
  unsigned short* hbf  = (unsigned short*)alloc((size_t)N_NODES * 64 * 2);
  unsigned short* ebuf = (unsigned short*)alloc((size_t)N_EDGES * 64 * 2);
  float* agg           = (float*)alloc((size_t)N_NODES * 64 * 4);
  float* xb0           = (float*)alloc((size_t)N_NODES * 3 * 4);
  float* xb1           = (float*)alloc((size_t)N_NODES * 3 * 4);
  int* cnt             = (int*)alloc((size_t)N_NODES * 4);
  int* rowptr          = (int*)alloc((size_t)(N_NODES + 1) * 4);
  int* cur             = (int*)alloc((size_t)N_NODES * 4);
  int* elist           = (int*)alloc((size_t)N_EDGES * 4);
  int* rsorted         = (int*)alloc((size_t)N_EDGES * 4);
  int* csorted         = (int*)alloc((size_t)N_EDGES * 4);
  float* msorted       = (float*)alloc((size_t)N_EDGES * 4);
  unsigned short* Wt1  = (unsigned short*)alloc((size_t)NLAYERS * 64 * K1PAD * 2);
  unsigned short* Wt2  = (unsigned short*)alloc((size_t)NLAYERS * 64 * 64 * 2);
  unsigned short* Wtc  = (unsigned short*)alloc((size_t)NLAYERS * 64 * 64 * 2);
  unsigned short* Wtn1 = (unsigned short*)alloc((size_t)NLAYERS * 64 * 128 * 2);
  unsigned short* Wtn2 = (unsigned short*)alloc((size_t)NLAYERS * 64 * 64 * 2);
  unsigned short* WoN  = (unsigned short*)alloc((size_t)16 * 64 * 2);
  unsigned short* WoE  = (unsigned short*)alloc((size_t)16 * 64 * 2);
  unsigned short* WtE  = (unsigned short*)alloc((size_t)64 * 32 * 2);

  float* out = (float*)d_out;

  // one-time CSR build + edge sort
  hipMemsetAsync(cnt, 0, (size_t)N_NODES * 4, stream);
  k_hist<<<(N_EDGES + 255) / 256, 256, 0, stream>>>(eidx, cnt);
  k_scan<<<1, 1024, 0, stream>>>(cnt, rowptr, cur);
  k_scatter<<<(N_EDGES + 255) / 256, 256, 0, stream>>>(eidx, emask, cur, elist,
                                                       rsorted, csorted, msorted);

  k_convW1<<<(NLAYERS * 64 * K1PAD + 255) / 256, 256, 0, stream>>>(eW1, Wt1);
  k_convT<<<(NLAYERS * 64 * 64 + 255) / 256, 256, 0, stream>>>(eW2, Wt2, 64);
  k_convT<<<(NLAYERS * 64 * 64 + 255) / 256, 256, 0, stream>>>(cW1, Wtc, 64);
  k_convT<<<(NLAYERS * 64 * 128 + 255) / 256, 256, 0, stream>>>(nW1, Wtn1, 128);
  k_convT<<<(NLAYERS * 64 * 64 + 255) / 256, 256, 0, stream>>>(nW2, Wtn2, 64);
  k_convHead<<<4, 256, 0, stream>>>(Wn_out, WoN, 16);
  k_convHead<<<4, 256, 0, stream>>>(We_out, WoE, 8);
  k_convEin<<<8, 256, 0, stream>>>(We_in, WtE);

  k_h0<<<(N_NODES * 64 + 255) / 256, 256, 0, stream>>>(in_h, Wn_in, bn_in, h, hbf);
  k_e0<<<NTILES, 256, 0, stream>>>(in_ea, WtE, be_in, elist, ebuf);
  // both x buffers start as in_x; node_kernel maintains the invariant.
  hipMemcpyAsync(xb0, in_x, (size_t)N_NODES * 3 * 4, hipMemcpyDeviceToDevice, stream);
  hipMemcpyAsync(xb1, in_x, (size_t)N_NODES * 3 * 4, hipMemcpyDeviceToDevice, stream);
  // agg zeroed once; node_kernel re-zeroes in place each layer after consuming
  hipMemsetAsync(agg, 0, (size_t)N_NODES * 64 * 4, stream);

  for (int l = 0; l < NLAYERS; l++) {
    float* xi = (l & 1) ? xb1 : xb0;
    float* xo = (l & 1) ? xb0 : xb1;
    edge_kernel<<<NTILES2, 256, 0, stream>>>(
        hbf, ebuf, xi, xo, agg, rsorted, csorted, msorted,
        Wt1 + (size_t)l * 64 * K1PAD, Wt2 + (size_t)l * 64 * 64, Wtc + (size_t)l * 64 * 64,
        eb1 + l * 64, eb2 + l * 64, cb1 + l * 64, cW2 + l * 64);
    float* xnext = (l == NLAYERS - 1) ? (out + 800000) : xi;
    node_kernel<<<(N_NODES + 127) / 128, 256, 0, stream>>>(
        h, hbf, agg, xo, xnext, nmask,
        Wtn1 + (size_t)l * 64 * 128, Wtn2 + (size_t)l * 64 * 64, nb1 + l * 64, nb2 + l * 64);
  }

  k_hout<<<(N_NODES + 63) / 64, 256, 0, stream>>>(hbf, WoN, bn_out, nmask, out);
  k_eout<<<NTILES, 256, 0, stream>>>(ebuf, WoE, be_out, emask, elist, out + 950000);
}